// Round 7
// baseline (862.088 us; speedup 1.0000x reference)
//
#include <hip/hip_runtime.h>

typedef float  f32x4 __attribute__((ext_vector_type(4)));
typedef short  s16x8 __attribute__((ext_vector_type(8)));

#define AS1 __attribute__((address_space(1)))
#define AS3 __attribute__((address_space(3)))

__device__ __forceinline__ void gload_lds16(const void* g, void* l) {
  __builtin_amdgcn_global_load_lds((AS1 void*)(g), (AS3 void*)(l), 16, 0, 0);
}

__device__ __forceinline__ void mfma_bf16(f32x4& d, s16x8 a, s16x8 b) {
  asm volatile("v_mfma_f32_16x16x32_bf16 %0, %1, %2, %0" : "+v"(d) : "v"(a), "v"(b));
}

__device__ __forceinline__ unsigned short f2bf(float f) {
  union { float f; unsigned u; } v; v.f = f;
  unsigned u = v.u;
  unsigned r = u + 0x7fffu + ((u >> 16) & 1u);   // round-to-nearest-even
  return (unsigned short)(r >> 16);
}
__device__ __forceinline__ float bf2f(unsigned short u) {
  union { unsigned u; float f; } v; v.u = ((unsigned)u) << 16; return v.f;
}

// ---------------- fp32 -> bf16 convert ----------------
__launch_bounds__(256)
__global__ void cvt_bf16(const float* __restrict__ in, unsigned short* __restrict__ out, int n4) {
  for (int i = blockIdx.x * blockDim.x + threadIdx.x; i < n4; i += gridDim.x * blockDim.x) {
    float4 v = ((const float4*)in)[i];
    ushort4 u;
    u.x = f2bf(v.x); u.y = f2bf(v.y); u.z = f2bf(v.z); u.w = f2bf(v.w);
    ((ushort4*)out)[i] = u;
  }
}

// ---------------- h0 init: copy fp32 + bf16 ----------------
__launch_bounds__(256)
__global__ void init_h(const float* __restrict__ hid, float* __restrict__ hA,
                       unsigned short* __restrict__ hbf) {
  int i = blockIdx.x * 256 + threadIdx.x;
  float4 v = ((const float4*)hid)[i];
  ((float4*)hA)[i] = v;
  ushort4 u; u.x = f2bf(v.x); u.y = f2bf(v.y); u.z = f2bf(v.z); u.w = f2bf(v.w);
  ((ushort4*)hbf)[i] = u;
}

// ---------------- embedding gather + relu -> bf16 ----------------
__launch_bounds__(256)
__global__ void embed_relu(const int* __restrict__ tgt, const float* __restrict__ emb,
                           unsigned short* __restrict__ xbf) {
  int bid = blockIdx.x;
  int t = bid >> 6, b = bid & 63;
  int tok = (t == 0) ? 1 : tgt[(t - 1) * 64 + b];
  int c = threadIdx.x;
  float4 v = ((const float4*)(emb + (size_t)tok * 1024))[c];
  v.x = fmaxf(v.x, 0.f); v.y = fmaxf(v.y, 0.f); v.z = fmaxf(v.z, 0.f); v.w = fmaxf(v.w, 0.f);
  ushort4 u; u.x = f2bf(v.x); u.y = f2bf(v.y); u.z = f2bf(v.z); u.w = f2bf(v.w);
  ((ushort4*)(xbf + (size_t)bid * 1024))[c] = u;
}

// ---------------- bf16 MFMA GEMM:  C[M,N] = A[M,K] @ B[N,K]^T + bias ----------------
template<bool STATS, bool OUTBF>
__launch_bounds__(256)
__global__ void gemm_bt(const unsigned short* __restrict__ A,   // [M,K] bf16
                        const unsigned short* __restrict__ B,   // [N,K] bf16
                        const float* __restrict__ bias,         // [N] fp32
                        float* __restrict__ Cf,                 // [M,N] fp32 (if !OUTBF)
                        unsigned short* __restrict__ Cb,        // [M,N] bf16 (if OUTBF)
                        float2* __restrict__ stats,             // [M, nTilesTotal]
                        int N, int K, int mTiles, int nTilesTotal) {
  __shared__ unsigned short As[128 * 32];
  __shared__ unsigned short Bs[128 * 32];
  __shared__ float2 sstat[2][128];

  const int tid = threadIdx.x;
  int bid = blockIdx.x;
  { // XCD swizzle (gridDim.x % 8 == 0 for all our launches)
    int q = gridDim.x >> 3;
    bid = (bid & 7) * q + (bid >> 3);
  }
  const int tileN = bid / mTiles;
  const int tileM = bid % mTiles;
  const int m0 = tileM * 128, n0 = tileN * 128;
  const int lane = tid & 63;
  const int w = tid >> 6, wr = w >> 1, wc = w & 1;
  const int lr = lane & 15, lg = lane >> 4;

  f32x4 acc[4][4];
#pragma unroll
  for (int m = 0; m < 4; ++m)
#pragma unroll
    for (int n = 0; n < 4; ++n) acc[m][n] = (f32x4){0.f, 0.f, 0.f, 0.f};

  const int arow = tid >> 2;
  const int k8 = (tid & 3) * 8;

  for (int kt = 0; kt < K; kt += 32) {
#pragma unroll
    for (int c = 0; c < 2; ++c) {
      gload_lds16(A + (size_t)(m0 + arow + c * 64) * K + kt + k8, &As[(arow + c * 64) * 32 + k8]);
      gload_lds16(B + (size_t)(n0 + arow + c * 64) * K + kt + k8, &Bs[(arow + c * 64) * 32 + k8]);
    }
    __syncthreads();
    s16x8 af[4], bfr[4];
#pragma unroll
    for (int m = 0; m < 4; ++m)
      af[m] = *reinterpret_cast<const s16x8*>(&As[(wr * 64 + m * 16 + lr) * 32 + lg * 8]);
#pragma unroll
    for (int n = 0; n < 4; ++n)
      bfr[n] = *reinterpret_cast<const s16x8*>(&Bs[(wc * 64 + n * 16 + lr) * 32 + lg * 8]);
#pragma unroll
    for (int m = 0; m < 4; ++m)
#pragma unroll
      for (int n = 0; n < 4; ++n) mfma_bf16(acc[m][n], af[m], bfr[n]);
    __syncthreads();
  }

  float bv[4];
#pragma unroll
  for (int n = 0; n < 4; ++n) bv[n] = bias[n0 + wc * 64 + n * 16 + lr];
#pragma unroll
  for (int m = 0; m < 4; ++m)
#pragma unroll
    for (int n = 0; n < 4; ++n)
#pragma unroll
      for (int j = 0; j < 4; ++j) acc[m][n][j] += bv[n];

  // store C  (C/D frag: col = lane&15, row = (lane>>4)*4 + reg)
#pragma unroll
  for (int m = 0; m < 4; ++m) {
    int rbase = m0 + wr * 64 + m * 16 + lg * 4;
#pragma unroll
    for (int j = 0; j < 4; ++j) {
      size_t roff = (size_t)(rbase + j) * N;
#pragma unroll
      for (int n = 0; n < 4; ++n) {
        size_t idx = roff + n0 + wc * 64 + n * 16 + lr;
        if (OUTBF) Cb[idx] = f2bf(acc[m][n][j]);
        else       Cf[idx] = acc[m][n][j];
      }
    }
  }

  if (STATS) {
#pragma unroll
    for (int m = 0; m < 4; ++m) {
#pragma unroll
      for (int j = 0; j < 4; ++j) {
        float vmax = acc[m][0][j];
#pragma unroll
        for (int n = 1; n < 4; ++n) vmax = fmaxf(vmax, acc[m][n][j]);
#pragma unroll
        for (int s = 1; s < 16; s <<= 1) vmax = fmaxf(vmax, __shfl_xor(vmax, s, 64));
        float ss = 0.f;
#pragma unroll
        for (int n = 0; n < 4; ++n) ss += __expf(acc[m][n][j] - vmax);
#pragma unroll
        for (int s = 1; s < 16; s <<= 1) ss += __shfl_xor(ss, s, 64);
        if (lr == 0) sstat[wc][wr * 64 + m * 16 + lg * 4 + j] = make_float2(vmax, ss);
      }
    }
    __syncthreads();
    if (tid < 128) {
      float2 a = sstat[0][tid], b = sstat[1][tid];
      float Mx = fmaxf(a.x, b.x);
      float S = a.y * __expf(a.x - Mx) + b.y * __expf(b.x - Mx);
      stats[(size_t)(m0 + tid) * nTilesTotal + tileN] = make_float2(Mx, S);
    }
  }
}

// ---------------- persistent GRU scan v3 ----------------
// v2 structure (deep prefetch, conflict-free LDS, register h-state) with two fixes:
//   * tanhf restored (exact R2-passing numerics; tanh_fast removed)
//   * barrier hardened with explicit __threadfence() on BOTH sides of the flag
//     publish/spin. CDNA L2 is write-back and per-XCD non-coherent; the fence's
//     compiler-emitted wbl2/inv cache ops guarantee the h-tile stores are globally
//     visible before the flag, and stale lines are discarded before remote reads —
//     independent of how atomic store-release happens to be lowered.
__launch_bounds__(256)
__global__ void gru_scan(const unsigned short* __restrict__ whh,  // [3072,1024] bf16
                         const float* __restrict__ gi,            // [32*64, 3072] fp32
                         const float* __restrict__ bhh,           // [3072]
                         float* __restrict__ h,                   // [64,1024] fp32 (init h0; final h_last)
                         unsigned short* __restrict__ outs_bf,    // [(L+1)*64*1024], slot0 = h0
                         unsigned* __restrict__ bar) {            // 64 flags, 128B apart; zeroed
  __shared__ char lds[96 * 1024];
  const int tid = threadIdx.x, lane = tid & 63, w = tid >> 6;
  const int lr = lane & 15, lg = lane >> 4;
  const int j0 = blockIdx.x * 16;

  // stage whh panel via global_load_lds; dest is lane-linear (tid*16)
  // subtile layout: chunk c = g*2048 + K*64 + rr*4 + ll
  //   holds whh[g*1024 + j0 + rr][K*32 + ll*8 .. +8]
  for (int c = tid; c < 6144; c += 256) {
    int g  = c >> 11;            // gate
    int c2 = c & 2047;
    int K  = c2 >> 6;            // k-group (32 elems)
    int rr = (c2 >> 2) & 15;     // whh row within gate slice
    int ll = c2 & 3;             // k-subchunk (8 elems)
    gload_lds16(whh + (size_t)(g * 1024 + j0 + rr) * 1024 + K * 32 + ll * 8,
                lds + (size_t)c * 16);
  }

  const int col = j0 + lr;
  const float b_r = bhh[col], b_z = bhh[1024 + col], b_n = bhh[2048 + col];
  const int hrow_off = (w * 16 + lr) * 1024;

  // h state in registers; gi ping-pong regs
  float hv[4], cr[4], cz[4], cn[4];
#pragma unroll
  for (int j = 0; j < 4; ++j) {
    int b = w * 16 + lg * 4 + j;
    hv[j] = h[(size_t)b * 1024 + col];
    size_t gb = (size_t)b * 3072 + col;
    cr[j] = gi[gb]; cz[j] = gi[gb + 1024]; cn[j] = gi[gb + 2048];
  }

  __syncthreads();   // drains staging vmcnt; LDS panel ready

  for (int t = 0; t < 32; ++t) {
    const unsigned short* hbf = outs_bf + (size_t)t * 65536;

    // (1) issue ALL 32 a-frag loads (one latency wall instead of eight)
    s16x8 af[32];
#pragma unroll
    for (int i = 0; i < 32; ++i)
      af[i] = *reinterpret_cast<const s16x8*>(hbf + hrow_off + i * 32 + lg * 8);

    // (2) prefetch next step's gi (independent of h)
    float nr[4], nz[4], nn[4];
    {
      int tn = (t < 31) ? t + 1 : 31;
#pragma unroll
      for (int j = 0; j < 4; ++j) {
        int b = w * 16 + lg * 4 + j;
        size_t gb = (size_t)(tn * 64 + b) * 3072 + col;
        nr[j] = gi[gb]; nz[j] = gi[gb + 1024]; nn[j] = gi[gb + 2048];
      }
    }

    // (3) MFMA: 96 per wave, conflict-free LDS b-frags
    f32x4 acc[3];
#pragma unroll
    for (int g = 0; g < 3; ++g) acc[g] = (f32x4){0.f, 0.f, 0.f, 0.f};
#pragma unroll
    for (int i = 0; i < 32; ++i) {
#pragma unroll
      for (int g = 0; g < 3; ++g) {
        s16x8 b = *reinterpret_cast<const s16x8*>(lds + (size_t)(g * 32 + i) * 1024 + lr * 64 + lg * 16);
        mfma_bf16(acc[g], af[i], b);
      }
    }

    // (4) gates + h update — arithmetic EXACTLY as the R2-passing version
    unsigned short* hbf_out = outs_bf + (size_t)(t + 1) * 65536;
#pragma unroll
    for (int j = 0; j < 4; ++j) {
      int b = w * 16 + lg * 4 + j;
      float hr = acc[0][j] + b_r;
      float hz = acc[1][j] + b_z;
      float hn = acc[2][j] + b_n;
      float r = 1.f / (1.f + __expf(-(cr[j] + hr)));
      float z = 1.f / (1.f + __expf(-(cz[j] + hz)));
      float n = tanhf(cn[j] + r * hn);
      hv[j] = n + z * (hv[j] - n);
      hbf_out[(size_t)b * 1024 + col] = f2bf(hv[j]);
      cr[j] = nr[j]; cz[j] = nz[j]; cn[j] = nn[j];
    }

    // (5) fenced flag-broadcast grid barrier (skip after last step)
    if (t < 31) {
      __syncthreads();     // all waves' h stores issued & drained (vmcnt(0) before s_barrier)
      __threadfence();     // device-scope release: wbL2 — dirty h lines reach coherence point
      if (tid == 0)
        __hip_atomic_store(&bar[blockIdx.x * 32], (unsigned)(t + 1),
                           __ATOMIC_RELEASE, __HIP_MEMORY_SCOPE_AGENT);
      if (tid < 64) {
        while (__hip_atomic_load(&bar[tid * 32], __ATOMIC_ACQUIRE,
                                 __HIP_MEMORY_SCOPE_AGENT) < (unsigned)(t + 1))
          __builtin_amdgcn_s_sleep(2);
      }
      __threadfence();     // device-scope acquire: inv — no stale L1/L2 lines for remote h
      __syncthreads();
    }
  }

  // write back final h (for copy_h)
#pragma unroll
  for (int j = 0; j < 4; ++j) {
    int b = w * 16 + lg * 4 + j;
    h[(size_t)b * 1024 + col] = hv[j];
  }
}

// ---------------- per-row logZ from tile partials ----------------
__launch_bounds__(256)
__global__ void reduce_logz(const float2* __restrict__ stats, float* __restrict__ logZ, int nt) {
  int gid = blockIdx.x * blockDim.x + threadIdx.x;
  int row = gid >> 6, lane = gid & 63;
  const float2* s = stats + (size_t)row * nt;
  float M = -3.4e38f;
  for (int i = lane; i < nt; i += 64) M = fmaxf(M, s[i].x);
#pragma unroll
  for (int sh = 1; sh < 64; sh <<= 1) M = fmaxf(M, __shfl_xor(M, sh, 64));
  float S = 0.f;
  for (int i = lane; i < nt; i += 64) S += s[i].y * __expf(s[i].x - M);
#pragma unroll
  for (int sh = 1; sh < 64; sh <<= 1) S += __shfl_xor(S, sh, 64);
  if (lane == 0) logZ[row] = M + logf(S);
}

// ---------------- fixup (fast path): bf16 logits -> fp32 log_probs ----------------
__launch_bounds__(256)
__global__ void fixup_bf(const unsigned short* __restrict__ lbf, const float* __restrict__ logZ,
                         float* __restrict__ out) {
  const int n8 = 2048 * 32000 / 8;
  for (int i = blockIdx.x * 256 + threadIdx.x; i < n8; i += gridDim.x * 256) {
    s16x8 v = reinterpret_cast<const s16x8*>(lbf)[i];
    float z = logZ[i / 4000];
    float4 o0, o1;
    o0.x = bf2f((unsigned short)v[0]) - z; o0.y = bf2f((unsigned short)v[1]) - z;
    o0.z = bf2f((unsigned short)v[2]) - z; o0.w = bf2f((unsigned short)v[3]) - z;
    o1.x = bf2f((unsigned short)v[4]) - z; o1.y = bf2f((unsigned short)v[5]) - z;
    o1.z = bf2f((unsigned short)v[6]) - z; o1.w = bf2f((unsigned short)v[7]) - z;
    reinterpret_cast<float4*>(out)[2 * i]     = o0;
    reinterpret_cast<float4*>(out)[2 * i + 1] = o1;
  }
}

// ---------------- fixup (fallback): in-place RMW on fp32 logits ----------------
__launch_bounds__(256)
__global__ void fixup_rmw(float* __restrict__ out, const float* __restrict__ logZ) {
  const size_t total4 = 65536000u / 4u;
  for (size_t i = blockIdx.x * (size_t)blockDim.x + threadIdx.x; i < total4;
       i += (size_t)gridDim.x * blockDim.x) {
    float4 v = ((float4*)out)[i];
    int row = (int)((i * 4) / 32000);
    float z = logZ[row];
    v.x -= z; v.y -= z; v.z -= z; v.w -= z;
    ((float4*)out)[i] = v;
  }
}

// ---------------- h_last copy ----------------
__launch_bounds__(256)
__global__ void copy_h(const float* __restrict__ src, float* __restrict__ dst) {
  int i = blockIdx.x * 256 + threadIdx.x;
  ((float4*)dst)[i] = ((const float4*)src)[i];
}

extern "C" void kernel_launch(void* const* d_in, const int* in_sizes, int n_in,
                              void* d_out, int out_size, void* d_ws, size_t ws_size,
                              hipStream_t stream) {
  const int*   target = (const int*)d_in[0];
  const float* hidden = (const float*)d_in[2];
  const float* emb    = (const float*)d_in[3];
  const float* wih    = (const float*)d_in[4];
  const float* whh    = (const float*)d_in[5];
  const float* bih    = (const float*)d_in[6];
  const float* bhh    = (const float*)d_in[7];
  const float* fcw    = (const float*)d_in[8];
  const float* fcb    = (const float*)d_in[9];
  float* out = (float*)d_out;

  const int L = 32, B = 64, H = 1024, V = 32000;
  const int LB = L * B;                 // 2048
  const int NT_LOGITS = V / 128;        // 250
  const int MT = LB / 128;              // 16

  char* ws = (char*)d_ws;
  size_t off = 0;
  auto alloc = [&](size_t bytes) -> void* {
    void* p = ws + off;
    off += (bytes + 255) & ~(size_t)255;
    return p;
  };
  unsigned short* wih_bf  = (unsigned short*)alloc((size_t)3 * H * H * 2);
  unsigned short* whh_bf  = (unsigned short*)alloc((size_t)3 * H * H * 2);
  unsigned short* fcw_bf  = (unsigned short*)alloc((size_t)V * H * 2);
  unsigned short* x_bf    = (unsigned short*)alloc((size_t)LB * H * 2);
  unsigned short* outs_bf = (unsigned short*)alloc((size_t)(L + 1) * B * H * 2);
  float*          gi      = (float*)alloc((size_t)LB * 3 * H * 4);
  float*          hA      = (float*)alloc((size_t)B * H * 4);
  float2*         stats   = (float2*)alloc((size_t)LB * NT_LOGITS * 8);
  float*          logZ    = (float*)alloc((size_t)LB * 4);
  unsigned*       bar     = (unsigned*)alloc(64 * 128);   // 64 flags, 128B apart
  size_t lbf_bytes = (size_t)LB * V * 2;
  unsigned short* lbf = (unsigned short*)(ws + off);
  bool big = (off + lbf_bytes) <= ws_size;
  (void)in_sizes; (void)n_in; (void)out_size;

  // weights -> bf16
  cvt_bf16<<<2048, 256, 0, stream>>>(wih, wih_bf, 3 * H * H / 4);
  cvt_bf16<<<2048, 256, 0, stream>>>(whh, whh_bf, 3 * H * H / 4);
  cvt_bf16<<<2048, 256, 0, stream>>>(fcw, fcw_bf, V * H / 4);

  // h0
  init_h<<<64, 256, 0, stream>>>(hidden, hA, outs_bf);

  // x = relu(emb[tokens]) -> bf16
  embed_relu<<<LB, 256, 0, stream>>>(target, emb, x_bf);

  // gi = x @ w_ih^T + b_ih   (M=2048, N=3072, K=1024)
  gemm_bt<false, false><<<(3 * H / 128) * MT, 256, 0, stream>>>(
      x_bf, wih_bf, bih, gi, nullptr, nullptr, 3 * H, H, MT, 3 * H / 128);

  // persistent GRU scan (flags zeroed each call -> deterministic replay)
  hipMemsetAsync(bar, 0, 64 * 128, stream);
  gru_scan<<<64, 256, 0, stream>>>(whh_bf, gi, bhh, hA, outs_bf, bar);

  // logits GEMM (M=2048, N=32000)
  if (big) {
    gemm_bt<true, true><<<NT_LOGITS * MT, 256, 0, stream>>>(
        outs_bf + (size_t)B * H, fcw_bf, fcb, nullptr, lbf, stats, V, H, MT, NT_LOGITS);
    reduce_logz<<<LB * 64 / 256, 256, 0, stream>>>(stats, logZ, NT_LOGITS);
    fixup_bf<<<2048, 256, 0, stream>>>(lbf, logZ, out);
  } else {
    gemm_bt<true, false><<<NT_LOGITS * MT, 256, 0, stream>>>(
        outs_bf + (size_t)B * H, fcw_bf, fcb, out, nullptr, stats, V, H, MT, NT_LOGITS);
    reduce_logz<<<LB * 64 / 256, 256, 0, stream>>>(stats, logZ, NT_LOGITS);
    fixup_rmw<<<2048, 256, 0, stream>>>(out, logZ);
  }

  // h_last
  copy_h<<<64, 256, 0, stream>>>(hA, out + (size_t)LB * V);
}

// Round 8
// 752.753 us; speedup vs baseline: 1.1452x; 1.1452x over previous
//
#include <hip/hip_runtime.h>

typedef float  f32x4 __attribute__((ext_vector_type(4)));
typedef short  s16x8 __attribute__((ext_vector_type(8)));

#define AS1 __attribute__((address_space(1)))
#define AS3 __attribute__((address_space(3)))

__device__ __forceinline__ void gload_lds16(const void* g, void* l) {
  __builtin_amdgcn_global_load_lds((AS1 void*)(g), (AS3 void*)(l), 16, 0, 0);
}

__device__ __forceinline__ void mfma_bf16(f32x4& d, s16x8 a, s16x8 b) {
  asm volatile("v_mfma_f32_16x16x32_bf16 %0, %1, %2, %0" : "+v"(d) : "v"(a), "v"(b));
}

// coherent (MALL-probing) 8B load: bypasses L1/L2 via sc0+sc1 — fresh cross-XCD data
__device__ __forceinline__ void cload_b64(unsigned long long& d, const unsigned long long* p) {
  asm volatile("global_load_dwordx2 %0, %1, off sc0 sc1" : "=v"(d) : "v"(p));
}

__device__ __forceinline__ unsigned short f2bf(float f) {
  union { float f; unsigned u; } v; v.f = f;
  unsigned u = v.u;
  unsigned r = u + 0x7fffu + ((u >> 16) & 1u);   // round-to-nearest-even
  return (unsigned short)(r >> 16);
}
__device__ __forceinline__ float bf2f(unsigned short u) {
  union { unsigned u; float f; } v; v.u = ((unsigned)u) << 16; return v.f;
}

// ---------------- fp32 -> bf16 convert ----------------
__launch_bounds__(256)
__global__ void cvt_bf16(const float* __restrict__ in, unsigned short* __restrict__ out, int n4) {
  for (int i = blockIdx.x * blockDim.x + threadIdx.x; i < n4; i += gridDim.x * blockDim.x) {
    float4 v = ((const float4*)in)[i];
    ushort4 u;
    u.x = f2bf(v.x); u.y = f2bf(v.y); u.z = f2bf(v.z); u.w = f2bf(v.w);
    ((ushort4*)out)[i] = u;
  }
}

// ---------------- h0 init: copy fp32 + bf16 ----------------
__launch_bounds__(256)
__global__ void init_h(const float* __restrict__ hid, float* __restrict__ hA,
                       unsigned short* __restrict__ hbf) {
  int i = blockIdx.x * 256 + threadIdx.x;
  float4 v = ((const float4*)hid)[i];
  ((float4*)hA)[i] = v;
  ushort4 u; u.x = f2bf(v.x); u.y = f2bf(v.y); u.z = f2bf(v.z); u.w = f2bf(v.w);
  ((ushort4*)hbf)[i] = u;
}

// ---------------- embedding gather + relu -> bf16 ----------------
__launch_bounds__(256)
__global__ void embed_relu(const int* __restrict__ tgt, const float* __restrict__ emb,
                           unsigned short* __restrict__ xbf) {
  int bid = blockIdx.x;
  int t = bid >> 6, b = bid & 63;
  int tok = (t == 0) ? 1 : tgt[(t - 1) * 64 + b];
  int c = threadIdx.x;
  float4 v = ((const float4*)(emb + (size_t)tok * 1024))[c];
  v.x = fmaxf(v.x, 0.f); v.y = fmaxf(v.y, 0.f); v.z = fmaxf(v.z, 0.f); v.w = fmaxf(v.w, 0.f);
  ushort4 u; u.x = f2bf(v.x); u.y = f2bf(v.y); u.z = f2bf(v.z); u.w = f2bf(v.w);
  ((ushort4*)(xbf + (size_t)bid * 1024))[c] = u;
}

// ---------------- bf16 MFMA GEMM:  C[M,N] = A[M,K] @ B[N,K]^T + bias ----------------
template<bool STATS, bool OUTBF>
__launch_bounds__(256)
__global__ void gemm_bt(const unsigned short* __restrict__ A,   // [M,K] bf16
                        const unsigned short* __restrict__ B,   // [N,K] bf16
                        const float* __restrict__ bias,         // [N] fp32
                        float* __restrict__ Cf,                 // [M,N] fp32 (if !OUTBF)
                        unsigned short* __restrict__ Cb,        // [M,N] bf16 (if OUTBF)
                        float2* __restrict__ stats,             // [M, nTilesTotal]
                        int N, int K, int mTiles, int nTilesTotal) {
  __shared__ unsigned short As[128 * 32];
  __shared__ unsigned short Bs[128 * 32];
  __shared__ float2 sstat[2][128];

  const int tid = threadIdx.x;
  int bid = blockIdx.x;
  { // XCD swizzle (gridDim.x % 8 == 0 for all our launches)
    int q = gridDim.x >> 3;
    bid = (bid & 7) * q + (bid >> 3);
  }
  const int tileN = bid / mTiles;
  const int tileM = bid % mTiles;
  const int m0 = tileM * 128, n0 = tileN * 128;
  const int lane = tid & 63;
  const int w = tid >> 6, wr = w >> 1, wc = w & 1;
  const int lr = lane & 15, lg = lane >> 4;

  f32x4 acc[4][4];
#pragma unroll
  for (int m = 0; m < 4; ++m)
#pragma unroll
    for (int n = 0; n < 4; ++n) acc[m][n] = (f32x4){0.f, 0.f, 0.f, 0.f};

  const int arow = tid >> 2;
  const int k8 = (tid & 3) * 8;

  for (int kt = 0; kt < K; kt += 32) {
#pragma unroll
    for (int c = 0; c < 2; ++c) {
      gload_lds16(A + (size_t)(m0 + arow + c * 64) * K + kt + k8, &As[(arow + c * 64) * 32 + k8]);
      gload_lds16(B + (size_t)(n0 + arow + c * 64) * K + kt + k8, &Bs[(arow + c * 64) * 32 + k8]);
    }
    __syncthreads();
    s16x8 af[4], bfr[4];
#pragma unroll
    for (int m = 0; m < 4; ++m)
      af[m] = *reinterpret_cast<const s16x8*>(&As[(wr * 64 + m * 16 + lr) * 32 + lg * 8]);
#pragma unroll
    for (int n = 0; n < 4; ++n)
      bfr[n] = *reinterpret_cast<const s16x8*>(&Bs[(wc * 64 + n * 16 + lr) * 32 + lg * 8]);
#pragma unroll
    for (int m = 0; m < 4; ++m)
#pragma unroll
      for (int n = 0; n < 4; ++n) mfma_bf16(acc[m][n], af[m], bfr[n]);
    __syncthreads();
  }

  float bv[4];
#pragma unroll
  for (int n = 0; n < 4; ++n) bv[n] = bias[n0 + wc * 64 + n * 16 + lr];
#pragma unroll
  for (int m = 0; m < 4; ++m)
#pragma unroll
    for (int n = 0; n < 4; ++n)
#pragma unroll
      for (int j = 0; j < 4; ++j) acc[m][n][j] += bv[n];

  // store C  (C/D frag: col = lane&15, row = (lane>>4)*4 + reg)
#pragma unroll
  for (int m = 0; m < 4; ++m) {
    int rbase = m0 + wr * 64 + m * 16 + lg * 4;
#pragma unroll
    for (int j = 0; j < 4; ++j) {
      size_t roff = (size_t)(rbase + j) * N;
#pragma unroll
      for (int n = 0; n < 4; ++n) {
        size_t idx = roff + n0 + wc * 64 + n * 16 + lr;
        if (OUTBF) Cb[idx] = f2bf(acc[m][n][j]);
        else       Cf[idx] = acc[m][n][j];
      }
    }
  }

  if (STATS) {
#pragma unroll
    for (int m = 0; m < 4; ++m) {
#pragma unroll
      for (int j = 0; j < 4; ++j) {
        float vmax = acc[m][0][j];
#pragma unroll
        for (int n = 1; n < 4; ++n) vmax = fmaxf(vmax, acc[m][n][j]);
#pragma unroll
        for (int s = 1; s < 16; s <<= 1) vmax = fmaxf(vmax, __shfl_xor(vmax, s, 64));
        float ss = 0.f;
#pragma unroll
        for (int n = 0; n < 4; ++n) ss += __expf(acc[m][n][j] - vmax);
#pragma unroll
        for (int s = 1; s < 16; s <<= 1) ss += __shfl_xor(ss, s, 64);
        if (lr == 0) sstat[wc][wr * 64 + m * 16 + lg * 4 + j] = make_float2(vmax, ss);
      }
    }
    __syncthreads();
    if (tid < 128) {
      float2 a = sstat[0][tid], b = sstat[1][tid];
      float Mx = fmaxf(a.x, b.x);
      float S = a.y * __expf(a.x - Mx) + b.y * __expf(b.x - Mx);
      stats[(size_t)(m0 + tid) * nTilesTotal + tileN] = make_float2(Mx, S);
    }
  }
}

// ---------------- persistent GRU scan v4: fence-free push-through exchange ----------
// 64 blocks x 256 threads; block owns 16 cols of each gate (LDS-resident w_hh slice).
// Transposed MFMA (D = [gate-cols][batch]) so each thread owns (batch b, 4 consecutive
// cols): h_out = ONE 8B relaxed agent atomic store (write-through to MALL, no wbl2);
// h_in = coherent sc0+sc1 loads (probe MALL, no inv). Barrier = vmcnt-drain + relaxed
// flag store + relaxed poll. No release/acquire fences -> no per-step L2 flush, which
// was the invariant ~14 us/step in v1-v3.
__launch_bounds__(256, 1)
__global__ void gru_scan(const unsigned short* __restrict__ whh,  // [3072,1024] bf16
                         const float* __restrict__ gi,            // [32*64, 3072] fp32
                         const float* __restrict__ bhh,           // [3072]
                         float* __restrict__ h,                   // [64,1024] fp32 (init h0; final h_last)
                         unsigned short* __restrict__ outs_bf,    // [(L+1)*64*1024], slot0 = h0
                         unsigned* __restrict__ bar) {            // 64 flags, 128B apart; zeroed
  __shared__ char lds[96 * 1024];
  const int tid = threadIdx.x, lane = tid & 63, w = tid >> 6;
  const int lr = lane & 15, lg = lane >> 4;
  const int j0 = blockIdx.x * 16;

  // stage whh slice; chunk (g,K) holds 16 rows x 32 k, lane-contiguous:
  //   lds[(g*32+K)*1024 + l*16] = whh[g*1024 + j0 + (l&15)][K*32 + (l>>4)*8 .. +8]
  for (int c = tid; c < 6144; c += 256) {
    int chunk = c >> 6, u = c & 63;
    int g = chunk >> 5, K = chunk & 31;
    gload_lds16(whh + (size_t)(g * 1024 + j0 + (u & 15)) * 1024 + K * 32 + (u >> 4) * 8,
                lds + (size_t)c * 16);
  }

  const int b  = w * 16 + lr;     // owned batch row (B-frag row = D col)
  const int c0 = j0 + lg * 4;     // first of 4 owned gate-cols (D rows)

  float4 bhr = *(const float4*)(bhh + c0);
  float4 bhz = *(const float4*)(bhh + 1024 + c0);
  float4 bhn = *(const float4*)(bhh + 2048 + c0);

  // h state for the 4 owned (b, c0+j) cells + current-step gi
  float4 hv = *(const float4*)(h + (size_t)b * 1024 + c0);
  float4 cr, cz, cn;
  {
    const float* g0 = gi + (size_t)b * 3072 + c0;
    cr = *(const float4*)(g0);
    cz = *(const float4*)(g0 + 1024);
    cn = *(const float4*)(g0 + 2048);
  }

  __syncthreads();   // staging drained (vmcnt(0) + barrier)

  for (int t = 0; t < 32; ++t) {
    // (1) issue ALL 64 coherent 8B h loads back-to-back (b's full 1024-elem row)
    const unsigned long long* hb =
        (const unsigned long long*)(outs_bf + (size_t)t * 65536 + (size_t)b * 1024);
    unsigned long long hq[64];
#pragma unroll
    for (int i = 0; i < 32; ++i) {
      cload_b64(hq[2 * i],     hb + i * 8 + lg * 2);
      cload_b64(hq[2 * i + 1], hb + i * 8 + lg * 2 + 1);
    }

    // (2) prefetch next step's gi under the coherent-load latency
    float4 nr, nz, nn;
    {
      int tn = (t < 31) ? t + 1 : 31;
      const float* gn = gi + ((size_t)tn * 64 + b) * 3072 + c0;
      nr = *(const float4*)(gn);
      nz = *(const float4*)(gn + 1024);
      nn = *(const float4*)(gn + 2048);
    }

    asm volatile("s_waitcnt vmcnt(0)" ::: "memory");
    __builtin_amdgcn_sched_barrier(0);   // rule #18: nothing hoists above the wait

    // (3) MFMA: D[gate-col][batch]; A = w_hh frag (LDS, lane-contiguous), B = h frag
    f32x4 acc[3];
#pragma unroll
    for (int g = 0; g < 3; ++g) acc[g] = (f32x4){0.f, 0.f, 0.f, 0.f};
#pragma unroll
    for (int i = 0; i < 32; ++i) {
      union { unsigned long long q[2]; s16x8 v; } u;
      u.q[0] = hq[2 * i]; u.q[1] = hq[2 * i + 1];
#pragma unroll
      for (int g = 0; g < 3; ++g) {
        s16x8 wf = *reinterpret_cast<const s16x8*>(lds + (size_t)(g * 32 + i) * 1024 + lane * 16);
        mfma_bf16(acc[g], wf, u.v);
      }
    }

    // (4) gates + h update; acc[g][j] = (h @ w_g^T)[b][c0+j]
    float hvv[4] = {hv.x, hv.y, hv.z, hv.w};
    float crr[4] = {cr.x, cr.y, cr.z, cr.w}, czz[4] = {cz.x, cz.y, cz.z, cz.w},
          cnn[4] = {cn.x, cn.y, cn.z, cn.w};
    float brr[4] = {bhr.x, bhr.y, bhr.z, bhr.w}, bzz[4] = {bhz.x, bhz.y, bhz.z, bhz.w},
          bnn[4] = {bhn.x, bhn.y, bhn.z, bhn.w};
    unsigned long long pk = 0;
#pragma unroll
    for (int j = 0; j < 4; ++j) {
      float r = 1.f / (1.f + __expf(-(crr[j] + acc[0][j] + brr[j])));
      float z = 1.f / (1.f + __expf(-(czz[j] + acc[1][j] + bzz[j])));
      float n = tanhf(cnn[j] + r * (acc[2][j] + bnn[j]));
      hvv[j] = n + z * (hvv[j] - n);
      pk |= (unsigned long long)f2bf(hvv[j]) << (16 * j);
    }
    hv = (float4){hvv[0], hvv[1], hvv[2], hvv[3]};
    cr = nr; cz = nz; cn = nn;

    // (5) write-through h_out: one relaxed agent-scope 8B atomic store (no wbl2)
    __hip_atomic_store(
        (unsigned long long*)(outs_bf + (size_t)(t + 1) * 65536 + (size_t)b * 1024 + c0),
        pk, __ATOMIC_RELAXED, __HIP_MEMORY_SCOPE_AGENT);

    // (6) fence-free barrier: drain stores, publish flag, poll flags (all relaxed)
    if (t < 31) {
      asm volatile("s_waitcnt vmcnt(0)" ::: "memory");  // h stores acked at MALL
      __syncthreads();
      if (tid == 0)
        __hip_atomic_store(&bar[blockIdx.x * 32], (unsigned)(t + 1),
                           __ATOMIC_RELAXED, __HIP_MEMORY_SCOPE_AGENT);
      if (tid < 64) {
        while (__hip_atomic_load(&bar[tid * 32], __ATOMIC_RELAXED,
                                 __HIP_MEMORY_SCOPE_AGENT) < (unsigned)(t + 1))
          __builtin_amdgcn_s_sleep(1);
      }
      __syncthreads();
    }
  }

  // write back final h (for copy_h)
  *(float4*)(h + (size_t)b * 1024 + c0) = hv;
}

// ---------------- per-row logZ from tile partials ----------------
__launch_bounds__(256)
__global__ void reduce_logz(const float2* __restrict__ stats, float* __restrict__ logZ, int nt) {
  int gid = blockIdx.x * blockDim.x + threadIdx.x;
  int row = gid >> 6, lane = gid & 63;
  const float2* s = stats + (size_t)row * nt;
  float M = -3.4e38f;
  for (int i = lane; i < nt; i += 64) M = fmaxf(M, s[i].x);
#pragma unroll
  for (int sh = 1; sh < 64; sh <<= 1) M = fmaxf(M, __shfl_xor(M, sh, 64));
  float S = 0.f;
  for (int i = lane; i < nt; i += 64) S += s[i].y * __expf(s[i].x - M);
#pragma unroll
  for (int sh = 1; sh < 64; sh <<= 1) S += __shfl_xor(S, sh, 64);
  if (lane == 0) logZ[row] = M + logf(S);
}

// ---------------- fixup (fast path): bf16 logits -> fp32 log_probs ----------------
__launch_bounds__(256)
__global__ void fixup_bf(const unsigned short* __restrict__ lbf, const float* __restrict__ logZ,
                         float* __restrict__ out) {
  const int n8 = 2048 * 32000 / 8;
  for (int i = blockIdx.x * 256 + threadIdx.x; i < n8; i += gridDim.x * 256) {
    s16x8 v = reinterpret_cast<const s16x8*>(lbf)[i];
    float z = logZ[i / 4000];
    float4 o0, o1;
    o0.x = bf2f((unsigned short)v[0]) - z; o0.y = bf2f((unsigned short)v[1]) - z;
    o0.z = bf2f((unsigned short)v[2]) - z; o0.w = bf2f((unsigned short)v[3]) - z;
    o1.x = bf2f((unsigned short)v[4]) - z; o1.y = bf2f((unsigned short)v[5]) - z;
    o1.z = bf2f((unsigned short)v[6]) - z; o1.w = bf2f((unsigned short)v[7]) - z;
    reinterpret_cast<float4*>(out)[2 * i]     = o0;
    reinterpret_cast<float4*>(out)[2 * i + 1] = o1;
  }
}

// ---------------- fixup (fallback): in-place RMW on fp32 logits ----------------
__launch_bounds__(256)
__global__ void fixup_rmw(float* __restrict__ out, const float* __restrict__ logZ) {
  const size_t total4 = 65536000u / 4u;
  for (size_t i = blockIdx.x * (size_t)blockDim.x + threadIdx.x; i < total4;
       i += (size_t)gridDim.x * blockDim.x) {
    float4 v = ((float4*)out)[i];
    int row = (int)((i * 4) / 32000);
    float z = logZ[row];
    v.x -= z; v.y -= z; v.z -= z; v.w -= z;
    ((float4*)out)[i] = v;
  }
}

// ---------------- h_last copy ----------------
__launch_bounds__(256)
__global__ void copy_h(const float* __restrict__ src, float* __restrict__ dst) {
  int i = blockIdx.x * 256 + threadIdx.x;
  ((float4*)dst)[i] = ((const float4*)src)[i];
}

extern "C" void kernel_launch(void* const* d_in, const int* in_sizes, int n_in,
                              void* d_out, int out_size, void* d_ws, size_t ws_size,
                              hipStream_t stream) {
  const int*   target = (const int*)d_in[0];
  const float* hidden = (const float*)d_in[2];
  const float* emb    = (const float*)d_in[3];
  const float* wih    = (const float*)d_in[4];
  const float* whh    = (const float*)d_in[5];
  const float* bih    = (const float*)d_in[6];
  const float* bhh    = (const float*)d_in[7];
  const float* fcw    = (const float*)d_in[8];
  const float* fcb    = (const float*)d_in[9];
  float* out = (float*)d_out;

  const int L = 32, B = 64, H = 1024, V = 32000;
  const int LB = L * B;                 // 2048
  const int NT_LOGITS = V / 128;        // 250
  const int MT = LB / 128;              // 16

  char* ws = (char*)d_ws;
  size_t off = 0;
  auto alloc = [&](size_t bytes) -> void* {
    void* p = ws + off;
    off += (bytes + 255) & ~(size_t)255;
    return p;
  };
  unsigned short* wih_bf  = (unsigned short*)alloc((size_t)3 * H * H * 2);
  unsigned short* whh_bf  = (unsigned short*)alloc((size_t)3 * H * H * 2);
  unsigned short* fcw_bf  = (unsigned short*)alloc((size_t)V * H * 2);
  unsigned short* x_bf    = (unsigned short*)alloc((size_t)LB * H * 2);
  unsigned short* outs_bf = (unsigned short*)alloc((size_t)(L + 1) * B * H * 2);
  float*          gi      = (float*)alloc((size_t)LB * 3 * H * 4);
  float*          hA      = (float*)alloc((size_t)B * H * 4);
  float2*         stats   = (float2*)alloc((size_t)LB * NT_LOGITS * 8);
  float*          logZ    = (float*)alloc((size_t)LB * 4);
  unsigned*       bar     = (unsigned*)alloc(64 * 128);   // 64 flags, 128B apart
  size_t lbf_bytes = (size_t)LB * V * 2;
  unsigned short* lbf = (unsigned short*)(ws + off);
  bool big = (off + lbf_bytes) <= ws_size;
  (void)in_sizes; (void)n_in; (void)out_size;

  // weights -> bf16
  cvt_bf16<<<2048, 256, 0, stream>>>(wih, wih_bf, 3 * H * H / 4);
  cvt_bf16<<<2048, 256, 0, stream>>>(whh, whh_bf, 3 * H * H / 4);
  cvt_bf16<<<2048, 256, 0, stream>>>(fcw, fcw_bf, V * H / 4);

  // h0
  init_h<<<64, 256, 0, stream>>>(hidden, hA, outs_bf);

  // x = relu(emb[tokens]) -> bf16
  embed_relu<<<LB, 256, 0, stream>>>(target, emb, x_bf);

  // gi = x @ w_ih^T + b_ih   (M=2048, N=3072, K=1024)
  gemm_bt<false, false><<<(3 * H / 128) * MT, 256, 0, stream>>>(
      x_bf, wih_bf, bih, gi, nullptr, nullptr, 3 * H, H, MT, 3 * H / 128);

  // persistent GRU scan (flags zeroed each call -> deterministic replay)
  hipMemsetAsync(bar, 0, 64 * 128, stream);
  gru_scan<<<64, 256, 0, stream>>>(whh_bf, gi, bhh, hA, outs_bf, bar);

  // logits GEMM (M=2048, N=32000)
  if (big) {
    gemm_bt<true, true><<<NT_LOGITS * MT, 256, 0, stream>>>(
        outs_bf + (size_t)B * H, fcw_bf, fcb, nullptr, lbf, stats, V, H, MT, NT_LOGITS);
    reduce_logz<<<LB * 64 / 256, 256, 0, stream>>>(stats, logZ, NT_LOGITS);
    fixup_bf<<<2048, 256, 0, stream>>>(lbf, logZ, out);
  } else {
    gemm_bt<true, false><<<NT_LOGITS * MT, 256, 0, stream>>>(
        outs_bf + (size_t)B * H, fcw_bf, fcb, out, nullptr, stats, V, H, MT, NT_LOGITS);
    reduce_logz<<<LB * 64 / 256, 256, 0, stream>>>(stats, logZ, NT_LOGITS);
    fixup_rmw<<<2048, 256, 0, stream>>>(out, logZ);
  }

  // h_last
  copy_h<<<64, 256, 0, stream>>>(hA, out + (size_t)LB * V);
}

// Round 9
// 691.672 us; speedup vs baseline: 1.2464x; 1.0883x over previous
//
#include <hip/hip_runtime.h>

typedef float  f32x4 __attribute__((ext_vector_type(4)));
typedef short  s16x8 __attribute__((ext_vector_type(8)));

#define AS1 __attribute__((address_space(1)))
#define AS3 __attribute__((address_space(3)))

__device__ __forceinline__ void gload_lds16(const void* g, void* l) {
  __builtin_amdgcn_global_load_lds((AS1 void*)(g), (AS3 void*)(l), 16, 0, 0);
}

__device__ __forceinline__ void mfma_bf16(f32x4& d, s16x8 a, s16x8 b) {
  asm volatile("v_mfma_f32_16x16x32_bf16 %0, %1, %2, %0" : "+v"(d) : "v"(a), "v"(b));
}

// coherent (MALL-probing) 8B load: bypasses L1/L2 via sc0+sc1 — fresh cross-XCD data
__device__ __forceinline__ void cload_b64(unsigned long long& d, const unsigned long long* p) {
  asm volatile("global_load_dwordx2 %0, %1, off sc0 sc1" : "=v"(d) : "v"(p));
}

__device__ __forceinline__ unsigned short f2bf(float f) {
  union { float f; unsigned u; } v; v.f = f;
  unsigned u = v.u;
  unsigned r = u + 0x7fffu + ((u >> 16) & 1u);   // round-to-nearest-even
  return (unsigned short)(r >> 16);
}
__device__ __forceinline__ float bf2f(unsigned short u) {
  union { unsigned u; float f; } v; v.u = ((unsigned)u) << 16; return v.f;
}

// ---------------- fp32 -> bf16 convert ----------------
__launch_bounds__(256)
__global__ void cvt_bf16(const float* __restrict__ in, unsigned short* __restrict__ out, int n4) {
  for (int i = blockIdx.x * blockDim.x + threadIdx.x; i < n4; i += gridDim.x * blockDim.x) {
    float4 v = ((const float4*)in)[i];
    ushort4 u;
    u.x = f2bf(v.x); u.y = f2bf(v.y); u.z = f2bf(v.z); u.w = f2bf(v.w);
    ((ushort4*)out)[i] = u;
  }
}

// ---------------- h0 init: copy fp32 + bf16 ----------------
__launch_bounds__(256)
__global__ void init_h(const float* __restrict__ hid, float* __restrict__ hA,
                       unsigned short* __restrict__ hbf) {
  int i = blockIdx.x * 256 + threadIdx.x;
  float4 v = ((const float4*)hid)[i];
  ((float4*)hA)[i] = v;
  ushort4 u; u.x = f2bf(v.x); u.y = f2bf(v.y); u.z = f2bf(v.z); u.w = f2bf(v.w);
  ((ushort4*)hbf)[i] = u;
}

// ---------------- embedding gather + relu -> bf16 ----------------
__launch_bounds__(256)
__global__ void embed_relu(const int* __restrict__ tgt, const float* __restrict__ emb,
                           unsigned short* __restrict__ xbf) {
  int bid = blockIdx.x;
  int t = bid >> 6, b = bid & 63;
  int tok = (t == 0) ? 1 : tgt[(t - 1) * 64 + b];
  int c = threadIdx.x;
  float4 v = ((const float4*)(emb + (size_t)tok * 1024))[c];
  v.x = fmaxf(v.x, 0.f); v.y = fmaxf(v.y, 0.f); v.z = fmaxf(v.z, 0.f); v.w = fmaxf(v.w, 0.f);
  ushort4 u; u.x = f2bf(v.x); u.y = f2bf(v.y); u.z = f2bf(v.z); u.w = f2bf(v.w);
  ((ushort4*)(xbf + (size_t)bid * 1024))[c] = u;
}

// ---------------- bf16 MFMA GEMM:  C[M,N] = A[M,K] @ B[N,K]^T + bias ----------------
template<bool STATS, bool OUTBF>
__launch_bounds__(256)
__global__ void gemm_bt(const unsigned short* __restrict__ A,   // [M,K] bf16
                        const unsigned short* __restrict__ B,   // [N,K] bf16
                        const float* __restrict__ bias,         // [N] fp32
                        float* __restrict__ Cf,                 // [M,N] fp32 (if !OUTBF)
                        unsigned short* __restrict__ Cb,        // [M,N] bf16 (if OUTBF)
                        float2* __restrict__ stats,             // [M, nTilesTotal]
                        int N, int K, int mTiles, int nTilesTotal) {
  __shared__ unsigned short As[128 * 32];
  __shared__ unsigned short Bs[128 * 32];
  __shared__ float2 sstat[2][128];

  const int tid = threadIdx.x;
  int bid = blockIdx.x;
  { // XCD swizzle (gridDim.x % 8 == 0 for all our launches)
    int q = gridDim.x >> 3;
    bid = (bid & 7) * q + (bid >> 3);
  }
  const int tileN = bid / mTiles;
  const int tileM = bid % mTiles;
  const int m0 = tileM * 128, n0 = tileN * 128;
  const int lane = tid & 63;
  const int w = tid >> 6, wr = w >> 1, wc = w & 1;
  const int lr = lane & 15, lg = lane >> 4;

  f32x4 acc[4][4];
#pragma unroll
  for (int m = 0; m < 4; ++m)
#pragma unroll
    for (int n = 0; n < 4; ++n) acc[m][n] = (f32x4){0.f, 0.f, 0.f, 0.f};

  const int arow = tid >> 2;
  const int k8 = (tid & 3) * 8;

  for (int kt = 0; kt < K; kt += 32) {
#pragma unroll
    for (int c = 0; c < 2; ++c) {
      gload_lds16(A + (size_t)(m0 + arow + c * 64) * K + kt + k8, &As[(arow + c * 64) * 32 + k8]);
      gload_lds16(B + (size_t)(n0 + arow + c * 64) * K + kt + k8, &Bs[(arow + c * 64) * 32 + k8]);
    }
    __syncthreads();
    s16x8 af[4], bfr[4];
#pragma unroll
    for (int m = 0; m < 4; ++m)
      af[m] = *reinterpret_cast<const s16x8*>(&As[(wr * 64 + m * 16 + lr) * 32 + lg * 8]);
#pragma unroll
    for (int n = 0; n < 4; ++n)
      bfr[n] = *reinterpret_cast<const s16x8*>(&Bs[(wc * 64 + n * 16 + lr) * 32 + lg * 8]);
#pragma unroll
    for (int m = 0; m < 4; ++m)
#pragma unroll
      for (int n = 0; n < 4; ++n) mfma_bf16(acc[m][n], af[m], bfr[n]);
    __syncthreads();
  }

  float bv[4];
#pragma unroll
  for (int n = 0; n < 4; ++n) bv[n] = bias[n0 + wc * 64 + n * 16 + lr];
#pragma unroll
  for (int m = 0; m < 4; ++m)
#pragma unroll
    for (int n = 0; n < 4; ++n)
#pragma unroll
      for (int j = 0; j < 4; ++j) acc[m][n][j] += bv[n];

  // store C  (C/D frag: col = lane&15, row = (lane>>4)*4 + reg)
#pragma unroll
  for (int m = 0; m < 4; ++m) {
    int rbase = m0 + wr * 64 + m * 16 + lg * 4;
#pragma unroll
    for (int j = 0; j < 4; ++j) {
      size_t roff = (size_t)(rbase + j) * N;
#pragma unroll
      for (int n = 0; n < 4; ++n) {
        size_t idx = roff + n0 + wc * 64 + n * 16 + lr;
        if (OUTBF) Cb[idx] = f2bf(acc[m][n][j]);
        else       Cf[idx] = acc[m][n][j];
      }
    }
  }

  if (STATS) {
#pragma unroll
    for (int m = 0; m < 4; ++m) {
#pragma unroll
      for (int j = 0; j < 4; ++j) {
        float vmax = acc[m][0][j];
#pragma unroll
        for (int n = 1; n < 4; ++n) vmax = fmaxf(vmax, acc[m][n][j]);
#pragma unroll
        for (int s = 1; s < 16; s <<= 1) vmax = fmaxf(vmax, __shfl_xor(vmax, s, 64));
        float ss = 0.f;
#pragma unroll
        for (int n = 0; n < 4; ++n) ss += __expf(acc[m][n][j] - vmax);
#pragma unroll
        for (int s = 1; s < 16; s <<= 1) ss += __shfl_xor(ss, s, 64);
        if (lr == 0) sstat[wc][wr * 64 + m * 16 + lg * 4 + j] = make_float2(vmax, ss);
      }
    }
    __syncthreads();
    if (tid < 128) {
      float2 a = sstat[0][tid], b = sstat[1][tid];
      float Mx = fmaxf(a.x, b.x);
      float S = a.y * __expf(a.x - Mx) + b.y * __expf(b.x - Mx);
      stats[(size_t)(m0 + tid) * nTilesTotal + tileN] = make_float2(Mx, S);
    }
  }
}

// ---------------- persistent GRU scan v5: chunked load/MFMA pipeline ----------------
// v4's fence-free exchange (write-through 8B atomic h stores, sc0+sc1 coherent h loads,
// relaxed flag barrier) UNCHANGED. Fix vs v4: the hq[64] prefetch array needed 128
// VGPRs but only 132 were allocated -> compiler spilled asm outputs to scratch and
// serialized the 64 MALL loads (~9.3 us/step). Now: 4 chunks of 16 qwords in two
// 32-VGPR arrays (qa/qb, reused), counted s_waitcnt vmcnt(16) between chunks (T4),
// MFMA of chunk k overlaps flight of chunk k+1. Peak liveness ~130 VGPR -> no spill.
__launch_bounds__(256, 1)
__global__ void gru_scan(const unsigned short* __restrict__ whh,  // [3072,1024] bf16
                         const float* __restrict__ gi,            // [32*64, 3072] fp32
                         const float* __restrict__ bhh,           // [3072]
                         float* __restrict__ h,                   // [64,1024] fp32 (init h0; final h_last)
                         unsigned short* __restrict__ outs_bf,    // [(L+1)*64*1024], slot0 = h0
                         unsigned* __restrict__ bar) {            // 64 flags, 128B apart; zeroed
  __shared__ char lds[96 * 1024];
  const int tid = threadIdx.x, lane = tid & 63, w = tid >> 6;
  const int lr = lane & 15, lg = lane >> 4;
  const int j0 = blockIdx.x * 16;

  // stage whh slice; chunk (g,K) holds 16 rows x 32 k, lane-contiguous:
  //   lds[(g*32+K)*1024 + l*16] = whh[g*1024 + j0 + (l&15)][K*32 + (l>>4)*8 .. +8]
  for (int c = tid; c < 6144; c += 256) {
    int chunk = c >> 6, u = c & 63;
    int g = chunk >> 5, K = chunk & 31;
    gload_lds16(whh + (size_t)(g * 1024 + j0 + (u & 15)) * 1024 + K * 32 + (u >> 4) * 8,
                lds + (size_t)c * 16);
  }

  const int b  = w * 16 + lr;     // owned batch row (B-frag col = D col)
  const int c0 = j0 + lg * 4;     // first of 4 owned gate-cols (D rows)

  float4 bhr = *(const float4*)(bhh + c0);
  float4 bhz = *(const float4*)(bhh + 1024 + c0);
  float4 bhn = *(const float4*)(bhh + 2048 + c0);

  // h state for the 4 owned (b, c0+j) cells + current-step gi
  float4 hv = *(const float4*)(h + (size_t)b * 1024 + c0);
  float4 cr, cz, cn;
  {
    const float* g0 = gi + (size_t)b * 3072 + c0;
    cr = *(const float4*)(g0);
    cz = *(const float4*)(g0 + 1024);
    cn = *(const float4*)(g0 + 2048);
  }

  __syncthreads();   // staging drained (vmcnt(0) + barrier)

  // chunk issue / consume helpers (all compile-time indices; volatile-ordered chain)
#define ISSUE_CHUNK(q, ibase)                                            \
  _Pragma("unroll")                                                      \
  for (int ii = 0; ii < 8; ++ii) {                                       \
    cload_b64(q[2 * ii],     hb + (ibase + ii) * 8 + lg * 2);            \
    cload_b64(q[2 * ii + 1], hb + (ibase + ii) * 8 + lg * 2 + 1);        \
  }
#define MFMA_CHUNK(q, ibase)                                             \
  _Pragma("unroll")                                                      \
  for (int ii = 0; ii < 8; ++ii) {                                       \
    union { unsigned long long q2[2]; s16x8 v; } u;                      \
    u.q2[0] = q[2 * ii]; u.q2[1] = q[2 * ii + 1];                        \
    _Pragma("unroll")                                                    \
    for (int g = 0; g < 3; ++g) {                                        \
      s16x8 wf = *reinterpret_cast<const s16x8*>(                        \
          lds + (size_t)(g * 32 + (ibase + ii)) * 1024 + lane * 16);     \
      mfma_bf16(acc[g], wf, u.v);                                        \
    }                                                                    \
  }
#define WAITV(n)                                               \
  asm volatile("s_waitcnt vmcnt(" #n ")" ::: "memory");        \
  __builtin_amdgcn_sched_barrier(0);

  for (int t = 0; t < 32; ++t) {
    const unsigned long long* hb =
        (const unsigned long long*)(outs_bf + (size_t)t * 65536 + (size_t)b * 1024);

    unsigned long long qa[16], qb[16];
    f32x4 acc[3];
#pragma unroll
    for (int g = 0; g < 3; ++g) acc[g] = (f32x4){0.f, 0.f, 0.f, 0.f};

    // prefetch next step's gi (normal loads; counted waits below are robust to
    // wherever the scheduler places these — see counting argument in journal)
    float4 nr, nz, nn;
    {
      int tn = (t < 31) ? t + 1 : 31;
      const float* gn = gi + ((size_t)tn * 64 + b) * 3072 + c0;
      nr = *(const float4*)(gn);
      nz = *(const float4*)(gn + 1024);
      nn = *(const float4*)(gn + 2048);
    }

    ISSUE_CHUNK(qa, 0)        // 16 loads in flight
    ISSUE_CHUNK(qb, 8)        // 32 in flight
    WAITV(16)                 // chunk0 (oldest 16 volatile loads) complete
    MFMA_CHUNK(qa, 0)
    ISSUE_CHUNK(qa, 16)       // reuse qa regs; 32 in flight
    WAITV(16)                 // chunk1 complete
    MFMA_CHUNK(qb, 8)
    ISSUE_CHUNK(qb, 24)
    WAITV(16)                 // chunk2 complete
    MFMA_CHUNK(qa, 16)
    WAITV(0)                  // chunk3 + gi drained
    MFMA_CHUNK(qb, 24)

    // gates + h update; acc[g][j] = (h @ w_g^T)[b][c0+j]
    float hvv[4] = {hv.x, hv.y, hv.z, hv.w};
    float crr[4] = {cr.x, cr.y, cr.z, cr.w}, czz[4] = {cz.x, cz.y, cz.z, cz.w},
          cnn[4] = {cn.x, cn.y, cn.z, cn.w};
    float brr[4] = {bhr.x, bhr.y, bhr.z, bhr.w}, bzz[4] = {bhz.x, bhz.y, bhz.z, bhz.w},
          bnn[4] = {bhn.x, bhn.y, bhn.z, bhn.w};
    unsigned long long pk = 0;
#pragma unroll
    for (int j = 0; j < 4; ++j) {
      float r = 1.f / (1.f + __expf(-(crr[j] + acc[0][j] + brr[j])));
      float z = 1.f / (1.f + __expf(-(czz[j] + acc[1][j] + bzz[j])));
      float n = tanhf(cnn[j] + r * (acc[2][j] + bnn[j]));
      hvv[j] = n + z * (hvv[j] - n);
      pk |= (unsigned long long)f2bf(hvv[j]) << (16 * j);
    }
    hv = (float4){hvv[0], hvv[1], hvv[2], hvv[3]};
    cr = nr; cz = nz; cn = nn;

    // write-through h_out: one relaxed agent-scope 8B atomic store (no wbl2)
    __hip_atomic_store(
        (unsigned long long*)(outs_bf + (size_t)(t + 1) * 65536 + (size_t)b * 1024 + c0),
        pk, __ATOMIC_RELAXED, __HIP_MEMORY_SCOPE_AGENT);

    // fence-free barrier: drain stores, publish flag, poll flags (all relaxed)
    if (t < 31) {
      asm volatile("s_waitcnt vmcnt(0)" ::: "memory");  // h stores acked at MALL
      __syncthreads();
      if (tid == 0)
        __hip_atomic_store(&bar[blockIdx.x * 32], (unsigned)(t + 1),
                           __ATOMIC_RELAXED, __HIP_MEMORY_SCOPE_AGENT);
      if (tid < 64) {
        while (__hip_atomic_load(&bar[tid * 32], __ATOMIC_RELAXED,
                                 __HIP_MEMORY_SCOPE_AGENT) < (unsigned)(t + 1))
          __builtin_amdgcn_s_sleep(1);
      }
      __syncthreads();
    }
  }
#undef ISSUE_CHUNK
#undef MFMA_CHUNK
#undef WAITV

  // write back final h (for copy_h)
  *(float4*)(h + (size_t)b * 1024 + c0) = hv;
}

// ---------------- per-row logZ from tile partials ----------------
__launch_bounds__(256)
__global__ void reduce_logz(const float2* __restrict__ stats, float* __restrict__ logZ, int nt) {
  int gid = blockIdx.x * blockDim.x + threadIdx.x;
  int row = gid >> 6, lane = gid & 63;
  const float2* s = stats + (size_t)row * nt;
  float M = -3.4e38f;
  for (int i = lane; i < nt; i += 64) M = fmaxf(M, s[i].x);
#pragma unroll
  for (int sh = 1; sh < 64; sh <<= 1) M = fmaxf(M, __shfl_xor(M, sh, 64));
  float S = 0.f;
  for (int i = lane; i < nt; i += 64) S += s[i].y * __expf(s[i].x - M);
#pragma unroll
  for (int sh = 1; sh < 64; sh <<= 1) S += __shfl_xor(S, sh, 64);
  if (lane == 0) logZ[row] = M + logf(S);
}

// ---------------- fixup (fast path): bf16 logits -> fp32 log_probs ----------------
__launch_bounds__(256)
__global__ void fixup_bf(const unsigned short* __restrict__ lbf, const float* __restrict__ logZ,
                         float* __restrict__ out) {
  const int n8 = 2048 * 32000 / 8;
  for (int i = blockIdx.x * 256 + threadIdx.x; i < n8; i += gridDim.x * 256) {
    s16x8 v = reinterpret_cast<const s16x8*>(lbf)[i];
    float z = logZ[i / 4000];
    float4 o0, o1;
    o0.x = bf2f((unsigned short)v[0]) - z; o0.y = bf2f((unsigned short)v[1]) - z;
    o0.z = bf2f((unsigned short)v[2]) - z; o0.w = bf2f((unsigned short)v[3]) - z;
    o1.x = bf2f((unsigned short)v[4]) - z; o1.y = bf2f((unsigned short)v[5]) - z;
    o1.z = bf2f((unsigned short)v[6]) - z; o1.w = bf2f((unsigned short)v[7]) - z;
    reinterpret_cast<float4*>(out)[2 * i]     = o0;
    reinterpret_cast<float4*>(out)[2 * i + 1] = o1;
  }
}

// ---------------- fixup (fallback): in-place RMW on fp32 logits ----------------
__launch_bounds__(256)
__global__ void fixup_rmw(float* __restrict__ out, const float* __restrict__ logZ) {
  const size_t total4 = 65536000u / 4u;
  for (size_t i = blockIdx.x * (size_t)blockDim.x + threadIdx.x; i < total4;
       i += (size_t)gridDim.x * blockDim.x) {
    float4 v = ((float4*)out)[i];
    int row = (int)((i * 4) / 32000);
    float z = logZ[row];
    v.x -= z; v.y -= z; v.z -= z; v.w -= z;
    ((float4*)out)[i] = v;
  }
}

// ---------------- h_last copy ----------------
__launch_bounds__(256)
__global__ void copy_h(const float* __restrict__ src, float* __restrict__ dst) {
  int i = blockIdx.x * 256 + threadIdx.x;
  ((float4*)dst)[i] = ((const float4*)src)[i];
}

extern "C" void kernel_launch(void* const* d_in, const int* in_sizes, int n_in,
                              void* d_out, int out_size, void* d_ws, size_t ws_size,
                              hipStream_t stream) {
  const int*   target = (const int*)d_in[0];
  const float* hidden = (const float*)d_in[2];
  const float* emb    = (const float*)d_in[3];
  const float* wih    = (const float*)d_in[4];
  const float* whh    = (const float*)d_in[5];
  const float* bih    = (const float*)d_in[6];
  const float* bhh    = (const float*)d_in[7];
  const float* fcw    = (const float*)d_in[8];
  const float* fcb    = (const float*)d_in[9];
  float* out = (float*)d_out;

  const int L = 32, B = 64, H = 1024, V = 32000;
  const int LB = L * B;                 // 2048
  const int NT_LOGITS = V / 128;        // 250
  const int MT = LB / 128;              // 16

  char* ws = (char*)d_ws;
  size_t off = 0;
  auto alloc = [&](size_t bytes) -> void* {
    void* p = ws + off;
    off += (bytes + 255) & ~(size_t)255;
    return p;
  };
  unsigned short* wih_bf  = (unsigned short*)alloc((size_t)3 * H * H * 2);
  unsigned short* whh_bf  = (unsigned short*)alloc((size_t)3 * H * H * 2);
  unsigned short* fcw_bf  = (unsigned short*)alloc((size_t)V * H * 2);
  unsigned short* x_bf    = (unsigned short*)alloc((size_t)LB * H * 2);
  unsigned short* outs_bf = (unsigned short*)alloc((size_t)(L + 1) * B * H * 2);
  float*          gi      = (float*)alloc((size_t)LB * 3 * H * 4);
  float*          hA      = (float*)alloc((size_t)B * H * 4);
  float2*         stats   = (float2*)alloc((size_t)LB * NT_LOGITS * 8);
  float*          logZ    = (float*)alloc((size_t)LB * 4);
  unsigned*       bar     = (unsigned*)alloc(64 * 128);   // 64 flags, 128B apart
  size_t lbf_bytes = (size_t)LB * V * 2;
  unsigned short* lbf = (unsigned short*)(ws + off);
  bool big = (off + lbf_bytes) <= ws_size;
  (void)in_sizes; (void)n_in; (void)out_size;

  // weights -> bf16
  cvt_bf16<<<2048, 256, 0, stream>>>(wih, wih_bf, 3 * H * H / 4);
  cvt_bf16<<<2048, 256, 0, stream>>>(whh, whh_bf, 3 * H * H / 4);
  cvt_bf16<<<2048, 256, 0, stream>>>(fcw, fcw_bf, V * H / 4);

  // h0
  init_h<<<64, 256, 0, stream>>>(hidden, hA, outs_bf);

  // x = relu(emb[tokens]) -> bf16
  embed_relu<<<LB, 256, 0, stream>>>(target, emb, x_bf);

  // gi = x @ w_ih^T + b_ih   (M=2048, N=3072, K=1024)
  gemm_bt<false, false><<<(3 * H / 128) * MT, 256, 0, stream>>>(
      x_bf, wih_bf, bih, gi, nullptr, nullptr, 3 * H, H, MT, 3 * H / 128);

  // persistent GRU scan (flags zeroed each call -> deterministic replay)
  hipMemsetAsync(bar, 0, 64 * 128, stream);
  gru_scan<<<64, 256, 0, stream>>>(whh_bf, gi, bhh, hA, outs_bf, bar);

  // logits GEMM (M=2048, N=32000)
  if (big) {
    gemm_bt<true, true><<<NT_LOGITS * MT, 256, 0, stream>>>(
        outs_bf + (size_t)B * H, fcw_bf, fcb, nullptr, lbf, stats, V, H, MT, NT_LOGITS);
    reduce_logz<<<LB * 64 / 256, 256, 0, stream>>>(stats, logZ, NT_LOGITS);
    fixup_bf<<<2048, 256, 0, stream>>>(lbf, logZ, out);
  } else {
    gemm_bt<true, false><<<NT_LOGITS * MT, 256, 0, stream>>>(
        outs_bf + (size_t)B * H, fcw_bf, fcb, out, nullptr, stats, V, H, MT, NT_LOGITS);
    reduce_logz<<<LB * 64 / 256, 256, 0, stream>>>(stats, logZ, NT_LOGITS);
    fixup_rmw<<<2048, 256, 0, stream>>>(out, logZ);
  }

  // h_last
  copy_h<<<64, 256, 0, stream>>>(hA, out + (size_t)LB * V);
}

// Round 10
// 600.508 us; speedup vs baseline: 1.4356x; 1.1518x over previous
//
#include <hip/hip_runtime.h>

typedef float  f32x4 __attribute__((ext_vector_type(4)));
typedef short  s16x8 __attribute__((ext_vector_type(8)));

#define AS1 __attribute__((address_space(1)))
#define AS3 __attribute__((address_space(3)))

__device__ __forceinline__ void gload_lds16(const void* g, void* l) {
  __builtin_amdgcn_global_load_lds((AS1 void*)(g), (AS3 void*)(l), 16, 0, 0);
}

__device__ __forceinline__ void mfma_bf16(f32x4& d, s16x8 a, s16x8 b) {
  asm volatile("v_mfma_f32_16x16x32_bf16 %0, %1, %2, %0" : "+v"(d) : "v"(a), "v"(b));
}

__device__ __forceinline__ unsigned short f2bf(float f) {
  union { float f; unsigned u; } v; v.f = f;
  unsigned u = v.u;
  unsigned r = u + 0x7fffu + ((u >> 16) & 1u);   // round-to-nearest-even
  return (unsigned short)(r >> 16);
}
__device__ __forceinline__ float bf2f(unsigned short u) {
  union { unsigned u; float f; } v; v.u = ((unsigned)u) << 16; return v.f;
}

// ---------------- fp32 -> bf16 convert ----------------
__launch_bounds__(256)
__global__ void cvt_bf16(const float* __restrict__ in, unsigned short* __restrict__ out, int n4) {
  for (int i = blockIdx.x * blockDim.x + threadIdx.x; i < n4; i += gridDim.x * blockDim.x) {
    float4 v = ((const float4*)in)[i];
    ushort4 u;
    u.x = f2bf(v.x); u.y = f2bf(v.y); u.z = f2bf(v.z); u.w = f2bf(v.w);
    ((ushort4*)out)[i] = u;
  }
}

// ---------------- h0 init: copy fp32 + bf16 ----------------
__launch_bounds__(256)
__global__ void init_h(const float* __restrict__ hid, float* __restrict__ hA,
                       unsigned short* __restrict__ hbf) {
  int i = blockIdx.x * 256 + threadIdx.x;
  float4 v = ((const float4*)hid)[i];
  ((float4*)hA)[i] = v;
  ushort4 u; u.x = f2bf(v.x); u.y = f2bf(v.y); u.z = f2bf(v.z); u.w = f2bf(v.w);
  ((ushort4*)hbf)[i] = u;
}

// ---------------- embedding gather + relu -> bf16 ----------------
__launch_bounds__(256)
__global__ void embed_relu(const int* __restrict__ tgt, const float* __restrict__ emb,
                           unsigned short* __restrict__ xbf) {
  int bid = blockIdx.x;
  int t = bid >> 6, b = bid & 63;
  int tok = (t == 0) ? 1 : tgt[(t - 1) * 64 + b];
  int c = threadIdx.x;
  float4 v = ((const float4*)(emb + (size_t)tok * 1024))[c];
  v.x = fmaxf(v.x, 0.f); v.y = fmaxf(v.y, 0.f); v.z = fmaxf(v.z, 0.f); v.w = fmaxf(v.w, 0.f);
  ushort4 u; u.x = f2bf(v.x); u.y = f2bf(v.y); u.z = f2bf(v.z); u.w = f2bf(v.w);
  ((ushort4*)(xbf + (size_t)bid * 1024))[c] = u;
}

// ---------------- bf16 MFMA GEMM:  C[M,N] = A[M,K] @ B[N,K]^T + bias ----------------
// v2: BK=64 (half the barrier pairs) + T2 XOR swizzle byte^=((row&7)<<4).
// global_load_lds needs a linear LDS dest, so the swizzle is applied by
// pre-swizzling the GLOBAL source offset (rule #21) and XOR-ing the read side.
template<bool STATS, bool OUTBF>
__launch_bounds__(256)
__global__ void gemm_bt(const unsigned short* __restrict__ A,   // [M,K] bf16
                        const unsigned short* __restrict__ B,   // [N,K] bf16
                        const float* __restrict__ bias,         // [N] fp32
                        float* __restrict__ Cf,                 // [M,N] fp32 (if !OUTBF)
                        unsigned short* __restrict__ Cb,        // [M,N] bf16 (if OUTBF)
                        float2* __restrict__ stats,             // [M, nTilesTotal]
                        int N, int K, int mTiles, int nTilesTotal) {
  __shared__ unsigned short As[128 * 64];
  __shared__ unsigned short Bs[128 * 64];
  __shared__ float2 sstat[2][128];

  const int tid = threadIdx.x;
  int bid = blockIdx.x;
  { // XCD swizzle (gridDim.x % 8 == 0 for all our launches)
    int q = gridDim.x >> 3;
    bid = (bid & 7) * q + (bid >> 3);
  }
  const int tileN = bid / mTiles;
  const int tileM = bid % mTiles;
  const int m0 = tileM * 128, n0 = tileN * 128;
  const int lane = tid & 63;
  const int w = tid >> 6, wr = w >> 1, wc = w & 1;
  const int lr = lane & 15, lg = lane >> 4;

  f32x4 acc[4][4];
#pragma unroll
  for (int m = 0; m < 4; ++m)
#pragma unroll
    for (int n = 0; n < 4; ++n) acc[m][n] = (f32x4){0.f, 0.f, 0.f, 0.f};

  const int crow = tid >> 3;          // staging row within 32-row group
  const int cj   = tid & 7;           // 16B slot within 128B row

  for (int kt = 0; kt < K; kt += 64) {
#pragma unroll
    for (int it = 0; it < 4; ++it) {
      int row = it * 32 + crow;
      int sb = ((cj * 16) ^ ((row & 7) << 4)) >> 1;   // pre-swizzled src elem offset
      gload_lds16(A + (size_t)(m0 + row) * K + kt + sb, &As[row * 64 + cj * 8]);
      gload_lds16(B + (size_t)(n0 + row) * K + kt + sb, &Bs[row * 64 + cj * 8]);
    }
    __syncthreads();
#pragma unroll
    for (int kk = 0; kk < 2; ++kk) {
      s16x8 af[4], bfr[4];
#pragma unroll
      for (int m = 0; m < 4; ++m) {
        int row = wr * 64 + m * 16 + lr;
        int off = ((kk * 64 + lg * 16) ^ ((row & 7) << 4)) >> 1;
        af[m] = *reinterpret_cast<const s16x8*>(&As[row * 64 + off]);
      }
#pragma unroll
      for (int n = 0; n < 4; ++n) {
        int row = wc * 64 + n * 16 + lr;
        int off = ((kk * 64 + lg * 16) ^ ((row & 7) << 4)) >> 1;
        bfr[n] = *reinterpret_cast<const s16x8*>(&Bs[row * 64 + off]);
      }
#pragma unroll
      for (int m = 0; m < 4; ++m)
#pragma unroll
        for (int n = 0; n < 4; ++n) mfma_bf16(acc[m][n], af[m], bfr[n]);
    }
    __syncthreads();
  }

  float bv[4];
#pragma unroll
  for (int n = 0; n < 4; ++n) bv[n] = bias[n0 + wc * 64 + n * 16 + lr];
#pragma unroll
  for (int m = 0; m < 4; ++m)
#pragma unroll
    for (int n = 0; n < 4; ++n)
#pragma unroll
      for (int j = 0; j < 4; ++j) acc[m][n][j] += bv[n];

  // store C  (C/D frag: col = lane&15, row = (lane>>4)*4 + reg)
#pragma unroll
  for (int m = 0; m < 4; ++m) {
    int rbase = m0 + wr * 64 + m * 16 + lg * 4;
#pragma unroll
    for (int j = 0; j < 4; ++j) {
      size_t roff = (size_t)(rbase + j) * N;
#pragma unroll
      for (int n = 0; n < 4; ++n) {
        size_t idx = roff + n0 + wc * 64 + n * 16 + lr;
        if (OUTBF) Cb[idx] = f2bf(acc[m][n][j]);
        else       Cf[idx] = acc[m][n][j];
      }
    }
  }

  if (STATS) {
#pragma unroll
    for (int m = 0; m < 4; ++m) {
#pragma unroll
      for (int j = 0; j < 4; ++j) {
        float vmax = acc[m][0][j];
#pragma unroll
        for (int n = 1; n < 4; ++n) vmax = fmaxf(vmax, acc[m][n][j]);
#pragma unroll
        for (int s = 1; s < 16; s <<= 1) vmax = fmaxf(vmax, __shfl_xor(vmax, s, 64));
        float ss = 0.f;
#pragma unroll
        for (int n = 0; n < 4; ++n) ss += __expf(acc[m][n][j] - vmax);
#pragma unroll
        for (int s = 1; s < 16; s <<= 1) ss += __shfl_xor(ss, s, 64);
        if (lr == 0) sstat[wc][wr * 64 + m * 16 + lg * 4 + j] = make_float2(vmax, ss);
      }
    }
    __syncthreads();
    if (tid < 128) {
      float2 a = sstat[0][tid], b = sstat[1][tid];
      float Mx = fmaxf(a.x, b.x);
      float S = a.y * __expf(a.x - Mx) + b.y * __expf(b.x - Mx);
      stats[(size_t)(m0 + tid) * nTilesTotal + tileN] = make_float2(Mx, S);
    }
  }
}

// ---------------- persistent GRU scan v6: cached-load exchange ----------------
// Diagnosis R9: sc0sc1 h loads pushed 8 MB/step through the MALL fine-grain path
// (~760 GB/s) -> throughput-bound, insensitive to load pipelining. Fix: NORMAL
// cached h loads. Safe because (a) kernel-dispatch acquire invalidates L2 at
// launch (the gi handoff already depends on this), (b) each outs_bf slot is
// written exactly once via WRITE-THROUGH atomic stores (no L2 copy exists), and
// (c) slot t is only read after the barrier for step t -> first touch per XCD
// misses to MALL (fresh), the rest hit XCD-local L2. MALL traffic: 8 MB -> 1 MB
// per step. Flag barrier unchanged (atomics remain sc0sc1-fresh).
__launch_bounds__(256, 1)
__global__ void gru_scan(const unsigned short* __restrict__ whh,  // [3072,1024] bf16
                         const float* __restrict__ gi,            // [32*64, 3072] fp32
                         const float* __restrict__ bhh,           // [3072]
                         float* __restrict__ h,                   // [64,1024] fp32 (init h0; final h_last)
                         unsigned short* __restrict__ outs_bf,    // [(L+1)*64*1024], slot0 = h0
                         unsigned* __restrict__ bar) {            // 64 flags, 128B apart; zeroed
  __shared__ char lds[96 * 1024];
  const int tid = threadIdx.x, lane = tid & 63, w = tid >> 6;
  const int lr = lane & 15, lg = lane >> 4;
  const int j0 = blockIdx.x * 16;

  // stage whh slice; chunk (g,K) holds 16 rows x 32 k, lane-contiguous:
  //   lds[(g*32+K)*1024 + l*16] = whh[g*1024 + j0 + (l&15)][K*32 + (l>>4)*8 .. +8]
  for (int c = tid; c < 6144; c += 256) {
    int chunk = c >> 6, u = c & 63;
    int g = chunk >> 5, K = chunk & 31;
    gload_lds16(whh + (size_t)(g * 1024 + j0 + (u & 15)) * 1024 + K * 32 + (u >> 4) * 8,
                lds + (size_t)c * 16);
  }

  const int b  = w * 16 + lr;     // owned batch row
  const int c0 = j0 + lg * 4;     // first of 4 owned gate-cols

  float4 bhr = *(const float4*)(bhh + c0);
  float4 bhz = *(const float4*)(bhh + 1024 + c0);
  float4 bhn = *(const float4*)(bhh + 2048 + c0);

  float4 hv = *(const float4*)(h + (size_t)b * 1024 + c0);
  float4 cr, cz, cn;
  {
    const float* g0 = gi + (size_t)b * 3072 + c0;
    cr = *(const float4*)(g0);
    cz = *(const float4*)(g0 + 1024);
    cn = *(const float4*)(g0 + 2048);
  }

  __syncthreads();   // staging drained (vmcnt(0) + barrier)

  for (int t = 0; t < 32; ++t) {
    // (1) load b's full h row, CACHED (XCD-local L2 after first touch).
    //     512 VGPR budget (launch_bounds 256,1): compiler can keep all 32 x 16B live.
    const s16x8* rowp =
        (const s16x8*)(outs_bf + (size_t)t * 65536 + (size_t)b * 1024);
    s16x8 hrow[32];
#pragma unroll
    for (int i = 0; i < 32; ++i) hrow[i] = rowp[i * 4 + lg];

    // (2) prefetch next step's gi
    float4 nr, nz, nn;
    {
      int tn = (t < 31) ? t + 1 : 31;
      const float* gn = gi + ((size_t)tn * 64 + b) * 3072 + c0;
      nr = *(const float4*)(gn);
      nz = *(const float4*)(gn + 1024);
      nn = *(const float4*)(gn + 2048);
    }

    // (3) MFMA: 96 per wave; conflict-free lane-contiguous LDS reads
    f32x4 acc[3];
#pragma unroll
    for (int g = 0; g < 3; ++g) acc[g] = (f32x4){0.f, 0.f, 0.f, 0.f};
#pragma unroll
    for (int i = 0; i < 32; ++i) {
#pragma unroll
      for (int g = 0; g < 3; ++g) {
        s16x8 wf = *reinterpret_cast<const s16x8*>(lds + (size_t)(g * 32 + i) * 1024 + lane * 16);
        mfma_bf16(acc[g], wf, hrow[i]);
      }
    }

    // (4) gates + h update
    float hvv[4] = {hv.x, hv.y, hv.z, hv.w};
    float crr[4] = {cr.x, cr.y, cr.z, cr.w}, czz[4] = {cz.x, cz.y, cz.z, cz.w},
          cnn[4] = {cn.x, cn.y, cn.z, cn.w};
    float brr[4] = {bhr.x, bhr.y, bhr.z, bhr.w}, bzz[4] = {bhz.x, bhz.y, bhz.z, bhz.w},
          bnn[4] = {bhn.x, bhn.y, bhn.z, bhn.w};
    unsigned long long pk = 0;
#pragma unroll
    for (int j = 0; j < 4; ++j) {
      float r = 1.f / (1.f + __expf(-(crr[j] + acc[0][j] + brr[j])));
      float z = 1.f / (1.f + __expf(-(czz[j] + acc[1][j] + bzz[j])));
      float n = tanhf(cnn[j] + r * (acc[2][j] + bnn[j]));
      hvv[j] = n + z * (hvv[j] - n);
      pk |= (unsigned long long)f2bf(hvv[j]) << (16 * j);
    }
    hv = (float4){hvv[0], hvv[1], hvv[2], hvv[3]};
    cr = nr; cz = nz; cn = nn;

    // (5) write-through h_out: one relaxed agent-scope 8B atomic store (no L2 copy)
    __hip_atomic_store(
        (unsigned long long*)(outs_bf + (size_t)(t + 1) * 65536 + (size_t)b * 1024 + c0),
        pk, __ATOMIC_RELAXED, __HIP_MEMORY_SCOPE_AGENT);

    // (6) fence-free barrier: drain stores, publish flag, poll flags (all relaxed)
    if (t < 31) {
      asm volatile("s_waitcnt vmcnt(0)" ::: "memory");  // h stores acked at MALL
      __syncthreads();
      if (tid == 0)
        __hip_atomic_store(&bar[blockIdx.x * 32], (unsigned)(t + 1),
                           __ATOMIC_RELAXED, __HIP_MEMORY_SCOPE_AGENT);
      if (tid < 64) {
        while (__hip_atomic_load(&bar[tid * 32], __ATOMIC_RELAXED,
                                 __HIP_MEMORY_SCOPE_AGENT) < (unsigned)(t + 1))
          __builtin_amdgcn_s_sleep(1);
      }
      __syncthreads();
    }
  }

  // write back final h (for copy_h)
  *(float4*)(h + (size_t)b * 1024 + c0) = hv;
}

// ---------------- per-row logZ from tile partials ----------------
__launch_bounds__(256)
__global__ void reduce_logz(const float2* __restrict__ stats, float* __restrict__ logZ, int nt) {
  int gid = blockIdx.x * blockDim.x + threadIdx.x;
  int row = gid >> 6, lane = gid & 63;
  const float2* s = stats + (size_t)row * nt;
  float M = -3.4e38f;
  for (int i = lane; i < nt; i += 64) M = fmaxf(M, s[i].x);
#pragma unroll
  for (int sh = 1; sh < 64; sh <<= 1) M = fmaxf(M, __shfl_xor(M, sh, 64));
  float S = 0.f;
  for (int i = lane; i < nt; i += 64) S += s[i].y * __expf(s[i].x - M);
#pragma unroll
  for (int sh = 1; sh < 64; sh <<= 1) S += __shfl_xor(S, sh, 64);
  if (lane == 0) logZ[row] = M + logf(S);
}

// ---------------- fixup (fast path): bf16 logits -> fp32 log_probs ----------------
__launch_bounds__(256)
__global__ void fixup_bf(const unsigned short* __restrict__ lbf, const float* __restrict__ logZ,
                         float* __restrict__ out) {
  const int n8 = 2048 * 32000 / 8;
  for (int i = blockIdx.x * 256 + threadIdx.x; i < n8; i += gridDim.x * 256) {
    s16x8 v = reinterpret_cast<const s16x8*>(lbf)[i];
    float z = logZ[i / 4000];
    float4 o0, o1;
    o0.x = bf2f((unsigned short)v[0]) - z; o0.y = bf2f((unsigned short)v[1]) - z;
    o0.z = bf2f((unsigned short)v[2]) - z; o0.w = bf2f((unsigned short)v[3]) - z;
    o1.x = bf2f((unsigned short)v[4]) - z; o1.y = bf2f((unsigned short)v[5]) - z;
    o1.z = bf2f((unsigned short)v[6]) - z; o1.w = bf2f((unsigned short)v[7]) - z;
    reinterpret_cast<float4*>(out)[2 * i]     = o0;
    reinterpret_cast<float4*>(out)[2 * i + 1] = o1;
  }
}

// ---------------- fixup (fallback): in-place RMW on fp32 logits ----------------
__launch_bounds__(256)
__global__ void fixup_rmw(float* __restrict__ out, const float* __restrict__ logZ) {
  const size_t total4 = 65536000u / 4u;
  for (size_t i = blockIdx.x * (size_t)blockDim.x + threadIdx.x; i < total4;
       i += (size_t)gridDim.x * blockDim.x) {
    float4 v = ((float4*)out)[i];
    int row = (int)((i * 4) / 32000);
    float z = logZ[row];
    v.x -= z; v.y -= z; v.z -= z; v.w -= z;
    ((float4*)out)[i] = v;
  }
}

// ---------------- h_last copy ----------------
__launch_bounds__(256)
__global__ void copy_h(const float* __restrict__ src, float* __restrict__ dst) {
  int i = blockIdx.x * 256 + threadIdx.x;
  ((float4*)dst)[i] = ((const float4*)src)[i];
}

extern "C" void kernel_launch(void* const* d_in, const int* in_sizes, int n_in,
                              void* d_out, int out_size, void* d_ws, size_t ws_size,
                              hipStream_t stream) {
  const int*   target = (const int*)d_in[0];
  const float* hidden = (const float*)d_in[2];
  const float* emb    = (const float*)d_in[3];
  const float* wih    = (const float*)d_in[4];
  const float* whh    = (const float*)d_in[5];
  const float* bih    = (const float*)d_in[6];
  const float* bhh    = (const float*)d_in[7];
  const float* fcw    = (const float*)d_in[8];
  const float* fcb    = (const float*)d_in[9];
  float* out = (float*)d_out;

  const int L = 32, B = 64, H = 1024, V = 32000;
  const int LB = L * B;                 // 2048
  const int NT_LOGITS = V / 128;        // 250
  const int MT = LB / 128;              // 16

  char* ws = (char*)d_ws;
  size_t off = 0;
  auto alloc = [&](size_t bytes) -> void* {
    void* p = ws + off;
    off += (bytes + 255) & ~(size_t)255;
    return p;
  };
  unsigned short* wih_bf  = (unsigned short*)alloc((size_t)3 * H * H * 2);
  unsigned short* whh_bf  = (unsigned short*)alloc((size_t)3 * H * H * 2);
  unsigned short* fcw_bf  = (unsigned short*)alloc((size_t)V * H * 2);
  unsigned short* x_bf    = (unsigned short*)alloc((size_t)LB * H * 2);
  unsigned short* outs_bf = (unsigned short*)alloc((size_t)(L + 1) * B * H * 2);
  float*          gi      = (float*)alloc((size_t)LB * 3 * H * 4);
  float*          hA      = (float*)alloc((size_t)B * H * 4);
  float2*         stats   = (float2*)alloc((size_t)LB * NT_LOGITS * 8);
  float*          logZ    = (float*)alloc((size_t)LB * 4);
  unsigned*       bar     = (unsigned*)alloc(64 * 128);   // 64 flags, 128B apart
  size_t lbf_bytes = (size_t)LB * V * 2;
  unsigned short* lbf = (unsigned short*)(ws + off);
  bool big = (off + lbf_bytes) <= ws_size;
  (void)in_sizes; (void)n_in; (void)out_size;

  // weights -> bf16
  cvt_bf16<<<2048, 256, 0, stream>>>(wih, wih_bf, 3 * H * H / 4);
  cvt_bf16<<<2048, 256, 0, stream>>>(whh, whh_bf, 3 * H * H / 4);
  cvt_bf16<<<2048, 256, 0, stream>>>(fcw, fcw_bf, V * H / 4);

  // h0
  init_h<<<64, 256, 0, stream>>>(hidden, hA, outs_bf);

  // x = relu(emb[tokens]) -> bf16
  embed_relu<<<LB, 256, 0, stream>>>(target, emb, x_bf);

  // gi = x @ w_ih^T + b_ih   (M=2048, N=3072, K=1024)
  gemm_bt<false, false><<<(3 * H / 128) * MT, 256, 0, stream>>>(
      x_bf, wih_bf, bih, gi, nullptr, nullptr, 3 * H, H, MT, 3 * H / 128);

  // persistent GRU scan (flags zeroed each call -> deterministic replay)
  hipMemsetAsync(bar, 0, 64 * 128, stream);
  gru_scan<<<64, 256, 0, stream>>>(whh_bf, gi, bhh, hA, outs_bf, bar);

  // logits GEMM (M=2048, N=32000)
  if (big) {
    gemm_bt<true, true><<<NT_LOGITS * MT, 256, 0, stream>>>(
        outs_bf + (size_t)B * H, fcw_bf, fcb, nullptr, lbf, stats, V, H, MT, NT_LOGITS);
    reduce_logz<<<LB * 64 / 256, 256, 0, stream>>>(stats, logZ, NT_LOGITS);
    fixup_bf<<<2048, 256, 0, stream>>>(lbf, logZ, out);
  } else {
    gemm_bt<true, false><<<NT_LOGITS * MT, 256, 0, stream>>>(
        outs_bf + (size_t)B * H, fcw_bf, fcb, out, nullptr, stats, V, H, MT, NT_LOGITS);
    reduce_logz<<<LB * 64 / 256, 256, 0, stream>>>(stats, logZ, NT_LOGITS);
    fixup_rmw<<<2048, 256, 0, stream>>>(out, logZ);
  }

  // h_last
  copy_h<<<64, 256, 0, stream>>>(hA, out + (size_t)LB * V);
}

// Round 11
// 576.107 us; speedup vs baseline: 1.4964x; 1.0424x over previous
//
#include <hip/hip_runtime.h>

typedef float  f32x4 __attribute__((ext_vector_type(4)));
typedef short  s16x8 __attribute__((ext_vector_type(8)));

#define AS1 __attribute__((address_space(1)))
#define AS3 __attribute__((address_space(3)))

__device__ __forceinline__ void gload_lds16(const void* g, void* l) {
  __builtin_amdgcn_global_load_lds((AS1 void*)(g), (AS3 void*)(l), 16, 0, 0);
}

__device__ __forceinline__ void mfma_bf16(f32x4& d, s16x8 a, s16x8 b) {
  asm volatile("v_mfma_f32_16x16x32_bf16 %0, %1, %2, %0" : "+v"(d) : "v"(a), "v"(b));
}

// cached 16B loads in explicit issue order (opaque to compiler waitcnt insertion)
__device__ __forceinline__ void gload_b128(s16x8& d, const void* p) {
  asm volatile("global_load_dwordx4 %0, %1, off" : "=v"(d) : "v"(p));
}
__device__ __forceinline__ void gload_f128(f32x4& d, const void* p) {
  asm volatile("global_load_dwordx4 %0, %1, off" : "=v"(d) : "v"(p));
}

__device__ __forceinline__ unsigned short f2bf(float f) {
  union { float f; unsigned u; } v; v.f = f;
  unsigned u = v.u;
  unsigned r = u + 0x7fffu + ((u >> 16) & 1u);   // round-to-nearest-even
  return (unsigned short)(r >> 16);
}
__device__ __forceinline__ float bf2f(unsigned short u) {
  union { unsigned u; float f; } v; v.u = ((unsigned)u) << 16; return v.f;
}

// ---------------- fp32 -> bf16 convert ----------------
__launch_bounds__(256)
__global__ void cvt_bf16(const float* __restrict__ in, unsigned short* __restrict__ out, int n4) {
  for (int i = blockIdx.x * blockDim.x + threadIdx.x; i < n4; i += gridDim.x * blockDim.x) {
    float4 v = ((const float4*)in)[i];
    ushort4 u;
    u.x = f2bf(v.x); u.y = f2bf(v.y); u.z = f2bf(v.z); u.w = f2bf(v.w);
    ((ushort4*)out)[i] = u;
  }
}

// ---------------- h0 init: copy fp32 + bf16 ----------------
__launch_bounds__(256)
__global__ void init_h(const float* __restrict__ hid, float* __restrict__ hA,
                       unsigned short* __restrict__ hbf) {
  int i = blockIdx.x * 256 + threadIdx.x;
  float4 v = ((const float4*)hid)[i];
  ((float4*)hA)[i] = v;
  ushort4 u; u.x = f2bf(v.x); u.y = f2bf(v.y); u.z = f2bf(v.z); u.w = f2bf(v.w);
  ((ushort4*)hbf)[i] = u;
}

// ---------------- embedding gather + relu -> bf16 ----------------
__launch_bounds__(256)
__global__ void embed_relu(const int* __restrict__ tgt, const float* __restrict__ emb,
                           unsigned short* __restrict__ xbf) {
  int bid = blockIdx.x;
  int t = bid >> 6, b = bid & 63;
  int tok = (t == 0) ? 1 : tgt[(t - 1) * 64 + b];
  int c = threadIdx.x;
  float4 v = ((const float4*)(emb + (size_t)tok * 1024))[c];
  v.x = fmaxf(v.x, 0.f); v.y = fmaxf(v.y, 0.f); v.z = fmaxf(v.z, 0.f); v.w = fmaxf(v.w, 0.f);
  ushort4 u; u.x = f2bf(v.x); u.y = f2bf(v.y); u.z = f2bf(v.z); u.w = f2bf(v.w);
  ((ushort4*)(xbf + (size_t)bid * 1024))[c] = u;
}

// ---------------- bf16 MFMA GEMM:  C[M,N] = A[M,K] @ B[N,K]^T + bias ----------------
// BK=64 + T2 XOR swizzle (pre-swizzled global source, rule #21). Unchanged from R10.
template<bool STATS, bool OUTBF>
__launch_bounds__(256)
__global__ void gemm_bt(const unsigned short* __restrict__ A,   // [M,K] bf16
                        const unsigned short* __restrict__ B,   // [N,K] bf16
                        const float* __restrict__ bias,         // [N] fp32
                        float* __restrict__ Cf,                 // [M,N] fp32 (if !OUTBF)
                        unsigned short* __restrict__ Cb,        // [M,N] bf16 (if OUTBF)
                        float2* __restrict__ stats,             // [M, nTilesTotal]
                        int N, int K, int mTiles, int nTilesTotal) {
  __shared__ unsigned short As[128 * 64];
  __shared__ unsigned short Bs[128 * 64];
  __shared__ float2 sstat[2][128];

  const int tid = threadIdx.x;
  int bid = blockIdx.x;
  { // XCD swizzle (gridDim.x % 8 == 0 for all our launches)
    int q = gridDim.x >> 3;
    bid = (bid & 7) * q + (bid >> 3);
  }
  const int tileN = bid / mTiles;
  const int tileM = bid % mTiles;
  const int m0 = tileM * 128, n0 = tileN * 128;
  const int lane = tid & 63;
  const int w = tid >> 6, wr = w >> 1, wc = w & 1;
  const int lr = lane & 15, lg = lane >> 4;

  f32x4 acc[4][4];
#pragma unroll
  for (int m = 0; m < 4; ++m)
#pragma unroll
    for (int n = 0; n < 4; ++n) acc[m][n] = (f32x4){0.f, 0.f, 0.f, 0.f};

  const int crow = tid >> 3;          // staging row within 32-row group
  const int cj   = tid & 7;           // 16B slot within 128B row

  for (int kt = 0; kt < K; kt += 64) {
#pragma unroll
    for (int it = 0; it < 4; ++it) {
      int row = it * 32 + crow;
      int sb = ((cj * 16) ^ ((row & 7) << 4)) >> 1;   // pre-swizzled src elem offset
      gload_lds16(A + (size_t)(m0 + row) * K + kt + sb, &As[row * 64 + cj * 8]);
      gload_lds16(B + (size_t)(n0 + row) * K + kt + sb, &Bs[row * 64 + cj * 8]);
    }
    __syncthreads();
#pragma unroll
    for (int kk = 0; kk < 2; ++kk) {
      s16x8 af[4], bfr[4];
#pragma unroll
      for (int m = 0; m < 4; ++m) {
        int row = wr * 64 + m * 16 + lr;
        int off = ((kk * 64 + lg * 16) ^ ((row & 7) << 4)) >> 1;
        af[m] = *reinterpret_cast<const s16x8*>(&As[row * 64 + off]);
      }
#pragma unroll
      for (int n = 0; n < 4; ++n) {
        int row = wc * 64 + n * 16 + lr;
        int off = ((kk * 64 + lg * 16) ^ ((row & 7) << 4)) >> 1;
        bfr[n] = *reinterpret_cast<const s16x8*>(&Bs[row * 64 + off]);
      }
#pragma unroll
      for (int m = 0; m < 4; ++m)
#pragma unroll
        for (int n = 0; n < 4; ++n) mfma_bf16(acc[m][n], af[m], bfr[n]);
    }
    __syncthreads();
  }

  float bv[4];
#pragma unroll
  for (int n = 0; n < 4; ++n) bv[n] = bias[n0 + wc * 64 + n * 16 + lr];
#pragma unroll
  for (int m = 0; m < 4; ++m)
#pragma unroll
    for (int n = 0; n < 4; ++n)
#pragma unroll
      for (int j = 0; j < 4; ++j) acc[m][n][j] += bv[n];

  // store C  (C/D frag: col = lane&15, row = (lane>>4)*4 + reg)
#pragma unroll
  for (int m = 0; m < 4; ++m) {
    int rbase = m0 + wr * 64 + m * 16 + lg * 4;
#pragma unroll
    for (int j = 0; j < 4; ++j) {
      size_t roff = (size_t)(rbase + j) * N;
#pragma unroll
      for (int n = 0; n < 4; ++n) {
        size_t idx = roff + n0 + wc * 64 + n * 16 + lr;
        if (OUTBF) Cb[idx] = f2bf(acc[m][n][j]);
        else       Cf[idx] = acc[m][n][j];
      }
    }
  }

  if (STATS) {
#pragma unroll
    for (int m = 0; m < 4; ++m) {
#pragma unroll
      for (int j = 0; j < 4; ++j) {
        float vmax = acc[m][0][j];
#pragma unroll
        for (int n = 1; n < 4; ++n) vmax = fmaxf(vmax, acc[m][n][j]);
#pragma unroll
        for (int s = 1; s < 16; s <<= 1) vmax = fmaxf(vmax, __shfl_xor(vmax, s, 64));
        float ss = 0.f;
#pragma unroll
        for (int n = 0; n < 4; ++n) ss += __expf(acc[m][n][j] - vmax);
#pragma unroll
        for (int s = 1; s < 16; s <<= 1) ss += __shfl_xor(ss, s, 64);
        if (lr == 0) sstat[wc][wr * 64 + m * 16 + lg * 4 + j] = make_float2(vmax, ss);
      }
    }
    __syncthreads();
    if (tid < 128) {
      float2 a = sstat[0][tid], b = sstat[1][tid];
      float Mx = fmaxf(a.x, b.x);
      float S = a.y * __expf(a.x - Mx) + b.y * __expf(b.x - Mx);
      stats[(size_t)(m0 + tid) * nTilesTotal + tileN] = make_float2(Mx, S);
    }
  }
}

// ---------------- persistent GRU scan v7: cached + chunk-pipelined loads ----------------
// v6 diagnosis: VGPR_Count stuck at 132 -> compiler never kept hrow[32] (128 VGPR)
// live; it serialized ~32 dependent L2 round-trips/step. v7: ALL h and gi loads are
// asm-volatile global_load_dwordx4 in fixed issue order (3 gi + 4 chunks of 8 h),
// gated by counted s_waitcnt vmcnt(8) (T4). Two 32-VGPR chunk arrays rotate; peak
// liveness ~140 VGPR, all static indices -> no spill. Loads fly 16-19 deep.
// Exchange semantics unchanged from v6 (cached reads safe; write-through stores).
__launch_bounds__(256, 1)
__global__ void gru_scan(const unsigned short* __restrict__ whh,  // [3072,1024] bf16
                         const float* __restrict__ gi,            // [32*64, 3072] fp32
                         const float* __restrict__ bhh,           // [3072]
                         float* __restrict__ h,                   // [64,1024] fp32 (init h0; final h_last)
                         unsigned short* __restrict__ outs_bf,    // [(L+1)*64*1024], slot0 = h0
                         unsigned* __restrict__ bar) {            // 64 flags, 128B apart; zeroed
  __shared__ char lds[96 * 1024];
  const int tid = threadIdx.x, lane = tid & 63, w = tid >> 6;
  const int lr = lane & 15, lg = lane >> 4;
  const int j0 = blockIdx.x * 16;

  // stage whh slice; chunk (g,K) holds 16 rows x 32 k, lane-contiguous:
  //   lds[(g*32+K)*1024 + l*16] = whh[g*1024 + j0 + (l&15)][K*32 + (l>>4)*8 .. +8]
  for (int c = tid; c < 6144; c += 256) {
    int chunk = c >> 6, u = c & 63;
    int g = chunk >> 5, K = chunk & 31;
    gload_lds16(whh + (size_t)(g * 1024 + j0 + (u & 15)) * 1024 + K * 32 + (u >> 4) * 8,
                lds + (size_t)c * 16);
  }

  const int b  = w * 16 + lr;     // owned batch row
  const int c0 = j0 + lg * 4;     // first of 4 owned gate-cols

  float4 bhr = *(const float4*)(bhh + c0);
  float4 bhz = *(const float4*)(bhh + 1024 + c0);
  float4 bhn = *(const float4*)(bhh + 2048 + c0);

  float4 hv = *(const float4*)(h + (size_t)b * 1024 + c0);
  f32x4 cr, cz, cn;
  {
    const float* g0 = gi + (size_t)b * 3072 + c0;
    cr = *(const f32x4*)(g0);
    cz = *(const f32x4*)(g0 + 1024);
    cn = *(const f32x4*)(g0 + 2048);
  }

  __syncthreads();   // staging drained (vmcnt(0) + barrier)

#define WAITV(n)                                               \
  asm volatile("s_waitcnt vmcnt(" #n ")" ::: "memory");        \
  __builtin_amdgcn_sched_barrier(0);
#define ISSUE8(q, ibase)                                       \
  _Pragma("unroll")                                            \
  for (int j = 0; j < 8; ++j)                                  \
    gload_b128(q[j], rowp + ((ibase) + j) * 4 + lg);
#define MFMA8(q, ibase)                                        \
  _Pragma("unroll")                                            \
  for (int j = 0; j < 8; ++j) {                                \
    _Pragma("unroll")                                          \
    for (int g = 0; g < 3; ++g) {                              \
      s16x8 wf = *reinterpret_cast<const s16x8*>(              \
          lds + (size_t)(g * 32 + (ibase) + j) * 1024 + lane * 16); \
      mfma_bf16(acc[g], wf, q[j]);                             \
    }                                                          \
  }

  for (int t = 0; t < 32; ++t) {
    const s16x8* rowp = (const s16x8*)(outs_bf + (size_t)t * 65536 + (size_t)b * 1024);

    // issue order (all asm, all counted): 3 gi + 8 qa + 8 qb
    f32x4 nr, nz, nn;
    {
      int tn = (t < 31) ? t + 1 : 31;
      const float* gn = gi + ((size_t)tn * 64 + b) * 3072 + c0;
      gload_f128(nr, gn);
      gload_f128(nz, gn + 1024);
      gload_f128(nn, gn + 2048);
    }
    s16x8 qa[8], qb[8];
    ISSUE8(qa, 0)            // out = 11
    ISSUE8(qb, 8)            // out = 19

    f32x4 acc[3];
#pragma unroll
    for (int g = 0; g < 3; ++g) acc[g] = (f32x4){0.f, 0.f, 0.f, 0.f};

    WAITV(8)                 // gi + qa done (qb may fly)
    MFMA8(qa, 0)
    ISSUE8(qa, 16)           // out <= 16
    WAITV(8)                 // qb done
    MFMA8(qb, 8)
    ISSUE8(qb, 24)           // out <= 16
    WAITV(8)                 // chunk2 done
    MFMA8(qa, 16)
    WAITV(0)                 // chunk3 done
    MFMA8(qb, 24)

    // gates + h update
    float hvv[4] = {hv.x, hv.y, hv.z, hv.w};
    float crr[4] = {cr[0], cr[1], cr[2], cr[3]}, czz[4] = {cz[0], cz[1], cz[2], cz[3]},
          cnn[4] = {cn[0], cn[1], cn[2], cn[3]};
    float brr[4] = {bhr.x, bhr.y, bhr.z, bhr.w}, bzz[4] = {bhz.x, bhz.y, bhz.z, bhz.w},
          bnn[4] = {bhn.x, bhn.y, bhn.z, bhn.w};
    unsigned long long pk = 0;
#pragma unroll
    for (int j = 0; j < 4; ++j) {
      float r = 1.f / (1.f + __expf(-(crr[j] + acc[0][j] + brr[j])));
      float z = 1.f / (1.f + __expf(-(czz[j] + acc[1][j] + bzz[j])));
      float n = tanhf(cnn[j] + r * (acc[2][j] + bnn[j]));
      hvv[j] = n + z * (hvv[j] - n);
      pk |= (unsigned long long)f2bf(hvv[j]) << (16 * j);
    }
    hv = (float4){hvv[0], hvv[1], hvv[2], hvv[3]};
    cr = nr; cz = nz; cn = nn;

    // write-through h_out: one relaxed agent-scope 8B atomic store (no L2 copy)
    __hip_atomic_store(
        (unsigned long long*)(outs_bf + (size_t)(t + 1) * 65536 + (size_t)b * 1024 + c0),
        pk, __ATOMIC_RELAXED, __HIP_MEMORY_SCOPE_AGENT);

    // fence-free barrier: drain stores, publish flag, poll flags (all relaxed)
    if (t < 31) {
      asm volatile("s_waitcnt vmcnt(0)" ::: "memory");  // h stores acked at MALL
      __syncthreads();
      if (tid == 0)
        __hip_atomic_store(&bar[blockIdx.x * 32], (unsigned)(t + 1),
                           __ATOMIC_RELAXED, __HIP_MEMORY_SCOPE_AGENT);
      if (tid < 64) {
        while (__hip_atomic_load(&bar[tid * 32], __ATOMIC_RELAXED,
                                 __HIP_MEMORY_SCOPE_AGENT) < (unsigned)(t + 1))
          __builtin_amdgcn_s_sleep(1);
      }
      __syncthreads();
    }
  }
#undef WAITV
#undef ISSUE8
#undef MFMA8

  // write back final h (for copy_h)
  *(float4*)(h + (size_t)b * 1024 + c0) = hv;
}

// ---------------- per-row logZ from tile partials ----------------
__launch_bounds__(256)
__global__ void reduce_logz(const float2* __restrict__ stats, float* __restrict__ logZ, int nt) {
  int gid = blockIdx.x * blockDim.x + threadIdx.x;
  int row = gid >> 6, lane = gid & 63;
  const float2* s = stats + (size_t)row * nt;
  float M = -3.4e38f;
  for (int i = lane; i < nt; i += 64) M = fmaxf(M, s[i].x);
#pragma unroll
  for (int sh = 1; sh < 64; sh <<= 1) M = fmaxf(M, __shfl_xor(M, sh, 64));
  float S = 0.f;
  for (int i = lane; i < nt; i += 64) S += s[i].y * __expf(s[i].x - M);
#pragma unroll
  for (int sh = 1; sh < 64; sh <<= 1) S += __shfl_xor(S, sh, 64);
  if (lane == 0) logZ[row] = M + logf(S);
}

// ---------------- fixup (fast path): bf16 logits -> fp32 log_probs ----------------
__launch_bounds__(256)
__global__ void fixup_bf(const unsigned short* __restrict__ lbf, const float* __restrict__ logZ,
                         float* __restrict__ out) {
  const int n8 = 2048 * 32000 / 8;
  for (int i = blockIdx.x * 256 + threadIdx.x; i < n8; i += gridDim.x * 256) {
    s16x8 v = reinterpret_cast<const s16x8*>(lbf)[i];
    float z = logZ[i / 4000];
    float4 o0, o1;
    o0.x = bf2f((unsigned short)v[0]) - z; o0.y = bf2f((unsigned short)v[1]) - z;
    o0.z = bf2f((unsigned short)v[2]) - z; o0.w = bf2f((unsigned short)v[3]) - z;
    o1.x = bf2f((unsigned short)v[4]) - z; o1.y = bf2f((unsigned short)v[5]) - z;
    o1.z = bf2f((unsigned short)v[6]) - z; o1.w = bf2f((unsigned short)v[7]) - z;
    reinterpret_cast<float4*>(out)[2 * i]     = o0;
    reinterpret_cast<float4*>(out)[2 * i + 1] = o1;
  }
}

// ---------------- fixup (fallback): in-place RMW on fp32 logits ----------------
__launch_bounds__(256)
__global__ void fixup_rmw(float* __restrict__ out, const float* __restrict__ logZ) {
  const size_t total4 = 65536000u / 4u;
  for (size_t i = blockIdx.x * (size_t)blockDim.x + threadIdx.x; i < total4;
       i += (size_t)gridDim.x * blockDim.x) {
    float4 v = ((float4*)out)[i];
    int row = (int)((i * 4) / 32000);
    float z = logZ[row];
    v.x -= z; v.y -= z; v.z -= z; v.w -= z;
    ((float4*)out)[i] = v;
  }
}

// ---------------- h_last copy ----------------
__launch_bounds__(256)
__global__ void copy_h(const float* __restrict__ src, float* __restrict__ dst) {
  int i = blockIdx.x * 256 + threadIdx.x;
  ((float4*)dst)[i] = ((const float4*)src)[i];
}

extern "C" void kernel_launch(void* const* d_in, const int* in_sizes, int n_in,
                              void* d_out, int out_size, void* d_ws, size_t ws_size,
                              hipStream_t stream) {
  const int*   target = (const int*)d_in[0];
  const float* hidden = (const float*)d_in[2];
  const float* emb    = (const float*)d_in[3];
  const float* wih    = (const float*)d_in[4];
  const float* whh    = (const float*)d_in[5];
  const float* bih    = (const float*)d_in[6];
  const float* bhh    = (const float*)d_in[7];
  const float* fcw    = (const float*)d_in[8];
  const float* fcb    = (const float*)d_in[9];
  float* out = (float*)d_out;

  const int L = 32, B = 64, H = 1024, V = 32000;
  const int LB = L * B;                 // 2048
  const int NT_LOGITS = V / 128;        // 250
  const int MT = LB / 128;              // 16

  char* ws = (char*)d_ws;
  size_t off = 0;
  auto alloc = [&](size_t bytes) -> void* {
    void* p = ws + off;
    off += (bytes + 255) & ~(size_t)255;
    return p;
  };
  unsigned short* wih_bf  = (unsigned short*)alloc((size_t)3 * H * H * 2);
  unsigned short* whh_bf  = (unsigned short*)alloc((size_t)3 * H * H * 2);
  unsigned short* fcw_bf  = (unsigned short*)alloc((size_t)V * H * 2);
  unsigned short* x_bf    = (unsigned short*)alloc((size_t)LB * H * 2);
  unsigned short* outs_bf = (unsigned short*)alloc((size_t)(L + 1) * B * H * 2);
  float*          gi      = (float*)alloc((size_t)LB * 3 * H * 4);
  float*          hA      = (float*)alloc((size_t)B * H * 4);
  float2*         stats   = (float2*)alloc((size_t)LB * NT_LOGITS * 8);
  float*          logZ    = (float*)alloc((size_t)LB * 4);
  unsigned*       bar     = (unsigned*)alloc(64 * 128);   // 64 flags, 128B apart
  size_t lbf_bytes = (size_t)LB * V * 2;
  unsigned short* lbf = (unsigned short*)(ws + off);
  bool big = (off + lbf_bytes) <= ws_size;
  (void)in_sizes; (void)n_in; (void)out_size;

  // weights -> bf16
  cvt_bf16<<<2048, 256, 0, stream>>>(wih, wih_bf, 3 * H * H / 4);
  cvt_bf16<<<2048, 256, 0, stream>>>(whh, whh_bf, 3 * H * H / 4);
  cvt_bf16<<<2048, 256, 0, stream>>>(fcw, fcw_bf, V * H / 4);

  // h0
  init_h<<<64, 256, 0, stream>>>(hidden, hA, outs_bf);

  // x = relu(emb[tokens]) -> bf16
  embed_relu<<<LB, 256, 0, stream>>>(target, emb, x_bf);

  // gi = x @ w_ih^T + b_ih   (M=2048, N=3072, K=1024)
  gemm_bt<false, false><<<(3 * H / 128) * MT, 256, 0, stream>>>(
      x_bf, wih_bf, bih, gi, nullptr, nullptr, 3 * H, H, MT, 3 * H / 128);

  // persistent GRU scan (flags zeroed each call -> deterministic replay)
  hipMemsetAsync(bar, 0, 64 * 128, stream);
  gru_scan<<<64, 256, 0, stream>>>(whh_bf, gi, bhh, hA, outs_bf, bar);

  // logits GEMM (M=2048, N=32000)
  if (big) {
    gemm_bt<true, true><<<NT_LOGITS * MT, 256, 0, stream>>>(
        outs_bf + (size_t)B * H, fcw_bf, fcb, nullptr, lbf, stats, V, H, MT, NT_LOGITS);
    reduce_logz<<<LB * 64 / 256, 256, 0, stream>>>(stats, logZ, NT_LOGITS);
    fixup_bf<<<2048, 256, 0, stream>>>(lbf, logZ, out);
  } else {
    gemm_bt<true, false><<<NT_LOGITS * MT, 256, 0, stream>>>(
        outs_bf + (size_t)B * H, fcw_bf, fcb, out, nullptr, stats, V, H, MT, NT_LOGITS);
    reduce_logz<<<LB * 64 / 256, 256, 0, stream>>>(stats, logZ, NT_LOGITS);
    fixup_rmw<<<2048, 256, 0, stream>>>(out, logZ);
  }

  // h_last
  copy_h<<<64, 256, 0, stream>>>(hA, out + (size_t)LB * V);
}